// Round 12
// baseline (149.388 us; speedup 1.0000x reference)
//
#include <hip/hip_runtime.h>

// B=2,N=2048,D=256,H=8,HD=32,DFF=1024. SCALE MULTIPLIES by sqrt(32). No MLP
// activation. Post-norm. Inputs fp32 (auto-detected), output fp32.
// R24: 141.2us. R25: 169.6 (Wmlp tail). R26: 144.7 (Wmlp first in qkvprep —
// still inflates qkvprep's critical path by ~15us; mlp collapse saved ~16).
//
// R27: Wmlp tiles moved into the ATTN dispatch (bids 0..15; attn at bid-16).
// Attn runs 2048 blocks / ~24us at 8 blocks/CU (16KB LDS) -> plenty of slack
// to hide 16 K=1024 tiles, and wmlp is only needed by dispatch 4 (mlp GEMM).
// qkvprep shrinks to 768 qkv + 21 small blocks (proj transpose, bmlp, params).
// 4 dispatches. Same math everywhere -> absmax unchanged.

typedef __attribute__((ext_vector_type(8))) short short8;       // raw 16B
typedef __attribute__((ext_vector_type(4))) short short4v;      // raw 8B
typedef __attribute__((ext_vector_type(8))) _Float16 half8;     // 8 fp16 = 4 VGPRs
typedef __attribute__((ext_vector_type(4))) _Float16 half4;     // 4 fp16 = 2 VGPRs
typedef __attribute__((ext_vector_type(2))) __fp16 fp16x2;      // cvt_pkrtz return type
typedef __attribute__((ext_vector_type(4))) float floatx4;
typedef __attribute__((ext_vector_type(2))) unsigned int uint2v;
typedef unsigned short u16;

#define MFMAG(a,b,c)  __builtin_amdgcn_mfma_f32_16x16x32_f16((a),(b),(c),0,0,0)
#if __has_builtin(__builtin_amdgcn_mfma_f32_16x16x16_f16)
#define MFMAPV(a,b,c) __builtin_amdgcn_mfma_f32_16x16x16_f16((a),(b),(c),0,0,0)
#else
#define MFMAPV(a,b,c) __builtin_amdgcn_mfma_f32_16x16x16f16((a),(b),(c),0,0,0)
#endif
#define CLF 8.1615404f   // SCALE * log2(e)

#if __has_builtin(__builtin_amdgcn_exp2f)
#define EX2(x) __builtin_amdgcn_exp2f(x)
#else
#define EX2(x) exp2f(x)
#endif

__device__ __forceinline__ float bf2f(u16 u) { return __uint_as_float(((unsigned)u) << 16); }
__device__ __forceinline__ float h2f(u16 u) { _Float16 h = *(_Float16*)&u; return (float)h; }
__device__ __forceinline__ u16 f2h(float f) { _Float16 h = (_Float16)f; return *(u16*)&h; }
// pack 2 fp32 -> 2 fp16 (RTZ), 1 VALU
__device__ __forceinline__ unsigned pkh2(float a, float b) {
#if __has_builtin(__builtin_amdgcn_cvt_pkrtz)
  fp16x2 h = __builtin_amdgcn_cvt_pkrtz(a, b);
  return *(unsigned*)&h;
#else
  return (unsigned)f2h(a) | ((unsigned)f2h(b) << 16);
#endif
}
// async global->LDS, 16B/lane; LDS dest = wave-uniform base + lane*16 (m104)
__device__ __forceinline__ void gll16(const void* g, void* l) {
  __builtin_amdgcn_global_load_lds((const __attribute__((address_space(1))) void*)g,
                                   (__attribute__((address_space(3))) void*)l, 16, 0, 0);
}

// ---------------- fused qkv GEMM + proj-transpose + bmlp + params ------------
// Grid 789 x 256 thr. Small prep blocks first:
// bid<16: proj_w transpose tiles; bid 16..19: bmlp quarters; bid 20: params.
// bid>=21: qkv 64x64 tile (qbid=bid-21: mb=qbid/12, nb=qbid%12), A=x raw,
//          B=qkv_w raw transposed-in-staging; epilogue Q->qf, K->kf, V->vt.
__global__ __launch_bounds__(256) void qkvprep_k(
    const void* __restrict__ x, const void* __restrict__ qkv_w,
    const void* __restrict__ proj_w, const void* __restrict__ proj_b,
    const void* __restrict__ fc1_b, const void* __restrict__ fc2_w,
    const void* __restrict__ fc2_b,
    const void* __restrict__ ln_g, const void* __restrict__ ln_b,
    u16* __restrict__ wt_proj, u16* __restrict__ bmlp,
    u16* __restrict__ b_proj, u16* __restrict__ g_ln, u16* __restrict__ bb_ln,
    u16* __restrict__ vt, u16* __restrict__ qf, u16* __restrict__ kf)
{
  __shared__ __align__(16) u16 lds[9728];   // As(2560)|Bs(2560)|Vt(4608); tr aliases
  const int tid = threadIdx.x;
  const int lane = tid & 63;
  const float probe = bf2f(((const u16*)qkv_w)[lane]);
  const bool f32 = __ballot(!(fabsf(probe) < 1000.0f)) != 0ull;
  const int bid = blockIdx.x;
  #define RD(p, i) (f32 ? ((const float*)(p))[i] : bf2f(((const u16*)(p))[i]))

  if (bid < 21) {
    int idx = bid;
    if (idx < 16) {               // ---- proj_w transpose tiles ----
      u16 (*tr)[70] = (u16(*)[70])lds;
      const int tk = idx & 3, tn = idx >> 2;
      const int k0 = tk * 64, n0v = tn * 64;
      const int r = tid >> 6, c = tid & 63;
#pragma unroll
      for (int p = 0; p < 16; ++p) {
        const int k = k0 + p * 4 + r;
        tr[c][p * 4 + r] = f2h(RD(proj_w, (size_t)k * 256 + n0v + c));
      }
      __syncthreads();
#pragma unroll
      for (int p = 0; p < 16; ++p) {
        const int n = n0v + p * 4 + r;
        wt_proj[(size_t)n * 256 + k0 + c] = tr[p * 4 + r][c];
      }
    } else if (idx < 20) {        // ---- bmlp quarter: n in [q*64, q*64+64) ----
      const int q = idx - 16;
      const int n = q * 64 + (tid >> 2), jg = tid & 3;
      float s = 0.f;
#pragma unroll 8
      for (int j = jg; j < 1024; j += 4)
        s += RD(fc1_b, j) * RD(fc2_w, (size_t)j * 256 + n);
      s += __shfl_xor(s, 1);
      s += __shfl_xor(s, 2);
      if (jg == 0) bmlp[n] = f2h(s + RD(fc2_b, n));
    } else {                      // ---- small fp16 params ----
      b_proj[tid] = f2h(RD(proj_b, tid));
      g_ln[tid]   = f2h(RD(ln_g, tid));
      bb_ln[tid]  = f2h(RD(ln_b, tid));
    }
    return;
  }

  // ---- qkv GEMM path ----
  u16 (*As)[40] = (u16(*)[40])lds;
  u16 (*Bs)[40] = (u16(*)[40])(lds + 2560);
  u16* Vt = lds + 5120;
  const int qbid = bid - 21;
  const int mb = qbid / 12, nb = qbid % 12;
  const int m0 = mb * 64, n0 = nb * 64;
  const int wid = tid >> 6;
  const int wm = (wid >> 1) * 32, wn = (wid & 1) * 32;
  const int lm = lane & 15, quad = lane >> 4;

  floatx4 zero = {0.f, 0.f, 0.f, 0.f};
  floatx4 acc[2][2] = {{zero, zero}, {zero, zero}};

  // staging: A: 4 thr/row x 8 k; B: thread owns col bn, k-octet bk8
  const int arow = tid >> 2, aoff = (tid & 3) * 8;
  const int bn = tid & 63, bk8 = (tid >> 6) * 8;

  short8 rah, rbh;
  auto ld = [&](int kk) {
    if (f32) {
      const float* xp = (const float*)x + (size_t)(m0 + arow) * 256 + kk + aoff;
      floatx4 a0 = *(const floatx4*)xp;
      floatx4 a1 = *(const floatx4*)(xp + 4);
#pragma unroll
      for (int j = 0; j < 4; ++j) {
        rah[j]     = (short)f2h(a0[j]);
        rah[4 + j] = (short)f2h(a1[j]);
      }
      const float* wp = (const float*)qkv_w + (size_t)(kk + bk8) * 768 + n0 + bn;
#pragma unroll
      for (int j = 0; j < 8; ++j) rbh[j] = (short)f2h(wp[(size_t)j * 768]);
    } else {
      short8 a = *(const short8*)((const u16*)x + (size_t)(m0 + arow) * 256 + kk + aoff);
#pragma unroll
      for (int j = 0; j < 8; ++j) rah[j] = (short)f2h(bf2f((u16)a[j]));
      const u16* wp = (const u16*)qkv_w + (size_t)(kk + bk8) * 768 + n0 + bn;
#pragma unroll
      for (int j = 0; j < 8; ++j) rbh[j] = (short)f2h(bf2f(wp[(size_t)j * 768]));
    }
  };
  ld(0);
  for (int k0 = 0; k0 < 256; k0 += 32) {
    if (k0) __syncthreads();
    *(short8*)&As[arow][aoff] = rah;
    *(short8*)&Bs[bn][bk8] = rbh;
    __syncthreads();
    if (k0 + 32 < 256) ld(k0 + 32);     // next-tile loads fly during MFMAs
    half8 fa[2], fb[2];
#pragma unroll
    for (int t = 0; t < 2; ++t) {
      fa[t] = *(const half8*)&As[wm + t * 16 + lm][quad * 8];
      fb[t] = *(const half8*)&Bs[wn + t * 16 + lm][quad * 8];
    }
#pragma unroll
    for (int i = 0; i < 2; ++i)
#pragma unroll
      for (int j = 0; j < 2; ++j)
        acc[i][j] = MFMAG(fa[i], fb[j], acc[i][j]);
  }
  #undef RD

  // ---- V epilogue (n0>=512): C -> LDS transpose -> coalesced vt rows ----
  if (n0 >= 512) {
    __syncthreads();
#pragma unroll
    for (int i = 0; i < 2; ++i)
#pragma unroll
      for (int j = 0; j < 2; ++j)
#pragma unroll
        for (int r = 0; r < 4; ++r)
          Vt[(wn + j * 16 + lm) * 72 + wm + i * 16 + quad * 4 + r] = f2h(acc[i][j][r]);
    __syncthreads();
    const int bb = m0 >> 11, n = m0 & 2047;
#pragma unroll
    for (int pass = 0; pass < 2; ++pass) {
      const int dl = (tid >> 3) + pass * 32;     // local col 0..63
      const int oct = tid & 7;                   // token octet
      const int col = n0 - 512 + dl;             // 0..255
      const int d = col & 31, hh = col >> 5;
      short8 v = *(const short8*)&Vt[dl * 72 + oct * 8];
      *(short8*)&vt[(size_t)((bb * 8 + hh) * 32 + d) * 2048 + n + oct * 8] = v;
    }
    return;
  }

  // ---- Q/K epilogue ----
#pragma unroll
  for (int i = 0; i < 2; ++i) {
    const int rowb = m0 + wm + i * 16 + quad * 4;
#pragma unroll
    for (int j = 0; j < 2; ++j) {
      const int col = n0 + wn + j * 16 + lm;
#pragma unroll
      for (int r = 0; r < 4; ++r) {
        const int row = rowb + r;
        const u16 hv = f2h(acc[i][j][r]);
        if (col < 256) qf[(size_t)row * 256 + col] = hv;
        else           kf[(size_t)row * 256 + (col - 256)] = hv;
      }
    }
  }
}

// ---------------- prep (FALLBACK paths only) ----------------
__global__ __launch_bounds__(256) void prep_k(
    const void* __restrict__ x, const void* __restrict__ qkv_w,
    const void* __restrict__ proj_w, const void* __restrict__ fc1_w,
    const void* __restrict__ fc2_w, const void* __restrict__ proj_b,
    const void* __restrict__ fc1_b, const void* __restrict__ fc2_b,
    const void* __restrict__ ln_g, const void* __restrict__ ln_b,
    u16* __restrict__ x_f, u16* __restrict__ wq_f,
    u16* __restrict__ wt_proj, u16* __restrict__ wt_fc1, u16* __restrict__ wt_fc2,
    u16* __restrict__ b_proj, u16* __restrict__ b_fc1, u16* __restrict__ b_fc2,
    u16* __restrict__ g_ln, u16* __restrict__ bb_ln)
{
  __shared__ u16 tr[64][70];
  const int lane = threadIdx.x & 63;
  const float probe = bf2f(((const u16*)qkv_w)[lane]);
  const bool f32 = __ballot(!(fabsf(probe) < 1000.0f)) != 0ull;
  const int bid = blockIdx.x, tid = threadIdx.x;
  #define RD(p, i) (f32 ? ((const float*)(p))[i] : bf2f(((const u16*)(p))[i]))
  if (bid < 1024) {
    const size_t i = (size_t)bid * 1024 + tid * 4;
    const u16 o0 = f2h(RD(x, i)),     o1 = f2h(RD(x, i + 1));
    const u16 o2 = f2h(RD(x, i + 2)), o3 = f2h(RD(x, i + 3));
    short4v sv = {(short)o0, (short)o1, (short)o2, (short)o3};
    *(short4v*)&x_f[i] = sv;
  } else if (bid < 1216) {
    int idx = bid - 1024;
    const void* src; u16* dst; int Ns, Kt, tk, tn;
    if (idx < 48)       { src = qkv_w;  dst = wq_f;    Ns = 768;  Kt = 256;
                          tk = idx & 3;  tn = idx >> 2; }
    else if (idx < 64)  { idx -= 48;  src = proj_w; dst = wt_proj; Ns = 256; Kt = 256;
                          tk = idx & 3;  tn = idx >> 2; }
    else if (idx < 128) { idx -= 64;  src = fc1_w;  dst = wt_fc1;  Ns = 1024; Kt = 256;
                          tk = idx & 3;  tn = idx >> 2; }
    else                { idx -= 128; src = fc2_w;  dst = wt_fc2;  Ns = 256;  Kt = 1024;
                          tk = idx & 15; tn = idx >> 4; }
    const int k0 = tk * 64, n0 = tn * 64;
    const int r = tid >> 6, c = tid & 63;
#pragma unroll
    for (int p = 0; p < 16; ++p) {
      const int k = k0 + p * 4 + r;
      tr[c][p * 4 + r] = f2h(RD(src, (size_t)k * Ns + n0 + c));
    }
    __syncthreads();
#pragma unroll
    for (int p = 0; p < 16; ++p) {
      const int n = n0 + p * 4 + r;
      dst[(size_t)n * Kt + k0 + c] = tr[p * 4 + r][c];
    }
  } else {
    const int j = (bid - 1216) * 256 + tid;
    if (j < 256)       b_proj[j]        = f2h(RD(proj_b, j));
    else if (j < 1280) b_fc1[j - 256]   = f2h(RD(fc1_b, j - 256));
    else if (j < 1536) b_fc2[j - 1280]  = f2h(RD(fc2_b, j - 1280));
    else if (j < 1792) g_ln[j - 1536]   = f2h(RD(ln_g, j - 1536));
    else if (j < 2048) bb_ln[j - 1792]  = f2h(RD(ln_b, j - 1792));
  }
  #undef RD
}

// ---------------- GEMM (fp16, fp32 accum) with register-prefetch staging ----------------
template<int TW, int EPI, bool BIAS, bool RES, bool COMB>
__global__ __launch_bounds__(256) void gemm_k(
    const u16* __restrict__ A, const u16* __restrict__ Bt, const u16* __restrict__ A2,
    const u16* __restrict__ bias, const u16* __restrict__ res,
    void* __restrict__ out0, u16* __restrict__ aux1, u16* __restrict__ aux3,
    const float* __restrict__ muc,
    int M, int Nn, int K)
{
  constexpr int BT = TW * 32;
  constexpr int NC = TW / 2;
  __shared__ __align__(16) u16 As[BT][40];
  __shared__ __align__(16) u16 Bs[BT][40];
  __shared__ __align__(16) u16 Vt[(EPI == 2) ? 64 * 72 : 1];
  const int tid = threadIdx.x;
  const int m0 = blockIdx.y * BT, n0 = blockIdx.x * BT;
  const int wid = tid >> 6, lane = tid & 63;
  const int wm = (wid >> 1) * (TW * 16), wn = (wid & 1) * (TW * 16);
  const int lm = lane & 15, quad = lane >> 4;

  floatx4 zero = {0.f, 0.f, 0.f, 0.f};
  floatx4 acc[TW][TW];
#pragma unroll
  for (int i = 0; i < TW; ++i)
#pragma unroll
    for (int j = 0; j < TW; ++j) acc[i][j] = zero;

  auto comb8 = [&](int t, int col8) -> short8 {
    const size_t o = (size_t)t * 256 + col8;
    const int h = col8 >> 5;
    const float m0_ = muc[t * 8 + h],          m1_ = muc[32768 + t * 8 + h];
    const float m2_ = muc[65536 + t * 8 + h],  m3_ = muc[98304 + t * 8 + h];
    const float M = fmaxf(fmaxf(m0_, m1_), fmaxf(m2_, m3_));
    float w0 = EX2(m0_ - M), w1 = EX2(m1_ - M), w2 = EX2(m2_ - M), w3 = EX2(m3_ - M);
    const float inv = 1.f / (w0 + w1 + w2 + w3);
    w0 *= inv; w1 *= inv; w2 *= inv; w3 *= inv;
    short8 a0 = *(const short8*)&A[o],  a1 = *(const short8*)&A[o + 1048576];
    short8 a2 = *(const short8*)&A2[o], a3 = *(const short8*)&A2[o + 1048576];
    float v[8];
#pragma unroll
    for (int j = 0; j < 8; ++j)
      v[j] = w0 * h2f((u16)a0[j]) + w1 * h2f((u16)a1[j])
           + w2 * h2f((u16)a2[j]) + w3 * h2f((u16)a3[j]);
    uint2v uu0 = {pkh2(v[0], v[1]), pkh2(v[2], v[3])};
    uint2v uu1 = {pkh2(v[4], v[5]), pkh2(v[6], v[7])};
    short8 r;
    *(uint2v*)&r = uu0; *((uint2v*)&r + 1) = uu1;
    return r;
  };

  int srow[NC], soff[NC];
#pragma unroll
  for (int c = 0; c < NC; ++c) {
    const int cid = tid * NC + c;
    srow[c] = cid >> 2; soff[c] = (cid & 3) * 8;
  }

  short8 ra0[NC], rb0[NC];
  auto ld = [&](int kk) {
#pragma unroll
    for (int c = 0; c < NC; ++c) {
      rb0[c] = *(const short8*)&Bt[(size_t)(n0 + srow[c]) * K + kk + soff[c]];
      if (COMB) ra0[c] = comb8(m0 + srow[c], kk + soff[c]);
      else      ra0[c] = *(const short8*)&A[(size_t)(m0 + srow[c]) * K + kk + soff[c]];
    }
  };
  ld(0);
  for (int k0 = 0; k0 < K; k0 += 32) {
    if (k0) __syncthreads();
#pragma unroll
    for (int c = 0; c < NC; ++c) {
      *(short8*)&As[srow[c]][soff[c]] = ra0[c];
      *(short8*)&Bs[srow[c]][soff[c]] = rb0[c];
    }
    __syncthreads();
    if (k0 + 32 < K) ld(k0 + 32);
    half8 fa[TW], fb[TW];
#pragma unroll
    for (int t = 0; t < TW; ++t) {
      fa[t] = *(const half8*)&As[wm + t * 16 + lm][quad * 8];
      fb[t] = *(const half8*)&Bs[wn + t * 16 + lm][quad * 8];
    }
#pragma unroll
    for (int i = 0; i < TW; ++i)
#pragma unroll
      for (int j = 0; j < TW; ++j)
        acc[i][j] = MFMAG(fa[i], fb[j], acc[i][j]);
  }

  if (EPI == 2 && n0 >= 512) {
    __syncthreads();
#pragma unroll
    for (int i = 0; i < TW; ++i)
#pragma unroll
      for (int j = 0; j < TW; ++j)
#pragma unroll
        for (int r = 0; r < 4; ++r)
          Vt[(wn + j * 16 + lm) * 72 + wm + i * 16 + quad * 4 + r] = f2h(acc[i][j][r]);
    __syncthreads();
    const int bb = m0 >> 11, n = m0 & 2047;
#pragma unroll
    for (int pass = 0; pass < 2; ++pass) {
      const int dl = (tid >> 3) + pass * 32;
      const int oct = tid & 7;
      const int col = n0 - 512 + dl;
      const int d = col & 31, hh = col >> 5;
      short8 v = *(const short8*)&Vt[dl * 72 + oct * 8];
      *(short8*)&((u16*)out0)[(size_t)((bb * 8 + hh) * 32 + d) * 2048 + n + oct * 8] = v;
    }
    return;
  }

#pragma unroll
  for (int i = 0; i < TW; ++i) {
    const int rowb = m0 + wm + i * 16 + quad * 4;
#pragma unroll
    for (int j = 0; j < TW; ++j) {
      const int col = n0 + wn + j * 16 + lm;
      const float bv = BIAS ? h2f(bias[col]) : 0.f;
#pragma unroll
      for (int r = 0; r < 4; ++r) {
        const int row = rowb + r;
        float v = acc[i][j][r] + bv;
        const size_t o = (size_t)row * Nn + col;
        if (RES) v += h2f(res[o]);
        if (EPI == 0) {
          ((float*)out0)[o] = v;
        } else if (EPI == 1) {
          ((u16*)out0)[o] = f2h(v);
        } else {
          if (col < 256) aux1[(size_t)row * 256 + col] = f2h(v);
          else           aux3[(size_t)row * 256 + (col - 256)] = f2h(v);
        }
      }
    }
  }
}

// ---------------- fused proj + combine + bias + residual(raw x) + LayerNorm (8 waves) ----
__global__ __launch_bounds__(512) void projln8_k(
    const u16* __restrict__ A,      // attn chunks 0,1
    const u16* __restrict__ A2,     // attn chunks 2,3
    const u16* __restrict__ Bt,     // wt_proj [256 n][256 k] fp16
    const u16* __restrict__ bias,   // b_proj fp16
    const void* __restrict__ xraw,  // raw x (fp32 or bf16)
    const void* __restrict__ probew,// qkv_w for dtype probe
    const u16* __restrict__ g, const u16* __restrict__ bb,
    const float* __restrict__ muc,
    u16* __restrict__ net)
{
  __shared__ __align__(16) u16 As[16][40];
  __shared__ __align__(16) u16 Bs[256][40];
  __shared__ float ss[8][16], ssq[8][16];
  const int tid = threadIdx.x;
  const int m0 = blockIdx.x * 16;
  const int wid = tid >> 6, lane = tid & 63;
  const int lm = lane & 15, quad = lane >> 4;
  const float probe = bf2f(((const u16*)probew)[lane]);
  const bool f32 = __ballot(!(fabsf(probe) < 1000.0f)) != 0ull;

  floatx4 zero = {0.f, 0.f, 0.f, 0.f};
  floatx4 acc0 = zero, acc1 = zero;

  auto comb8 = [&](int t, int col8) -> short8 {
    const size_t o = (size_t)t * 256 + col8;
    const int h = col8 >> 5;
    const float m0_ = muc[t * 8 + h],          m1_ = muc[32768 + t * 8 + h];
    const float m2_ = muc[65536 + t * 8 + h],  m3_ = muc[98304 + t * 8 + h];
    const float M = fmaxf(fmaxf(m0_, m1_), fmaxf(m2_, m3_));
    float w0 = EX2(m0_ - M), w1 = EX2(m1_ - M), w2 = EX2(m2_ - M), w3 = EX2(m3_ - M);
    const float inv = 1.f / (w0 + w1 + w2 + w3);
    w0 *= inv; w1 *= inv; w2 *= inv; w3 *= inv;
    short8 a0 = *(const short8*)&A[o],  a1 = *(const short8*)&A[o + 1048576];
    short8 a2 = *(const short8*)&A2[o], a3 = *(const short8*)&A2[o + 1048576];
    float v[8];
#pragma unroll
    for (int j = 0; j < 8; ++j)
      v[j] = w0 * h2f((u16)a0[j]) + w1 * h2f((u16)a1[j])
           + w2 * h2f((u16)a2[j]) + w3 * h2f((u16)a3[j]);
    uint2v uu0 = {pkh2(v[0], v[1]), pkh2(v[2], v[3])};
    uint2v uu1 = {pkh2(v[4], v[5]), pkh2(v[6], v[7])};
    short8 r;
    *(uint2v*)&r = uu0; *((uint2v*)&r + 1) = uu1;
    return r;
  };

  const int arow = lane >> 2, aoff = (lane & 3) * 8;
  int brow0 = wid * 32 + (lane >> 2), brow1 = brow0 + 16;
  const int boff = (lane & 3) * 8;

  short8 ra, rb0, rb1;
  if (wid == 0) ra = comb8(m0 + arow, aoff);
  rb0 = *(const short8*)&Bt[(size_t)brow0 * 256 + boff];
  rb1 = *(const short8*)&Bt[(size_t)brow1 * 256 + boff];

  for (int k0 = 0; k0 < 256; k0 += 32) {
    if (k0) __syncthreads();
    if (wid == 0) *(short8*)&As[arow][aoff] = ra;
    *(short8*)&Bs[brow0][boff] = rb0;
    *(short8*)&Bs[brow1][boff] = rb1;
    __syncthreads();
    if (k0 + 32 < 256) {
      if (wid == 0) ra = comb8(m0 + arow, k0 + 32 + aoff);
      rb0 = *(const short8*)&Bt[(size_t)brow0 * 256 + k0 + 32 + boff];
      rb1 = *(const short8*)&Bt[(size_t)brow1 * 256 + k0 + 32 + boff];
    }
    half8 fa = *(const half8*)&As[lm][quad * 8];
    half8 fb0 = *(const half8*)&Bs[wid * 32 + lm][quad * 8];
    half8 fb1 = *(const half8*)&Bs[wid * 32 + 16 + lm][quad * 8];
    acc0 = MFMAG(fa, fb0, acc0);
    acc1 = MFMAG(fa, fb1, acc1);
  }

  const int col0 = wid * 32 + lm, col1 = col0 + 16;
  const float bv0 = h2f(bias[col0]), bv1 = h2f(bias[col1]);
  float s[4], sq[4], v0[4], v1[4];
#pragma unroll
  for (int r = 0; r < 4; ++r) {
    const int row = quad * 4 + r;
    const size_t o0 = (size_t)(m0 + row) * 256 + col0;
    const size_t o1 = (size_t)(m0 + row) * 256 + col1;
    const float x0 = f32 ? ((const float*)xraw)[o0] : bf2f(((const u16*)xraw)[o0]);
    const float x1 = f32 ? ((const float*)xraw)[o1] : bf2f(((const u16*)xraw)[o1]);
    const float a = acc0[r] + bv0 + h2f(f2h(x0));   // keep x->fp16->fp32 value path
    const float b = acc1[r] + bv1 + h2f(f2h(x1));
    v0[r] = a; v1[r] = b;
    s[r] = a + b; sq[r] = a * a + b * b;
  }
#pragma unroll
  for (int d = 1; d < 16; d <<= 1)
#pragma unroll
    for (int r = 0; r < 4; ++r) {
      s[r] += __shfl_xor(s[r], d);
      sq[r] += __shfl_xor(sq[r], d);
    }
  if (lm == 0)
#pragma unroll
    for (int r = 0; r < 4; ++r) { ss[wid][quad * 4 + r] = s[r]; ssq[wid][quad * 4 + r] = sq[r]; }
  __syncthreads();
#pragma unroll
  for (int r = 0; r < 4; ++r) {
    const int row = quad * 4 + r;
    float ts = 0.f, tq = 0.f;
#pragma unroll
    for (int w = 0; w < 8; ++w) { ts += ss[w][row]; tq += ssq[w][row]; }
    const float mean = ts * (1.f / 256.f);
    const float var = tq * (1.f / 256.f) - mean * mean;
    const float is = rsqrtf(var + 1e-5f);
    net[(size_t)(m0 + row) * 256 + col0] =
        f2h((v0[r] - mean) * is * h2f(g[col0]) + h2f(bb[col0]));
    net[(size_t)(m0 + row) * 256 + col1] =
        f2h((v1[r] - mean) * is * h2f(g[col1]) + h2f(bb[col1]));
  }
}

// ---------------- flash attention (+ optional Wmlp tiles at bids 0..15) ----
// WMLP=true: bids 0..15 compute Wmlp[n][k] = sum_j W2[j][n]*W1[k][j] (K=1024);
// attention blocks decode abid = bid - 16.
template<int CHUNKS, bool WMLP>
__global__ __launch_bounds__(256) void attn_k(
    const u16* __restrict__ qf16, const u16* __restrict__ kf16,
    const u16* __restrict__ vt, u16* __restrict__ outp, u16* __restrict__ out23,
    float* __restrict__ mu,
    const void* __restrict__ fc1_w, const void* __restrict__ fc2_w,
    u16* __restrict__ wmlp)
{
  __shared__ __align__(16) u16 Ks[2][64][32];    // [buf][key][d] fp16 (8KB)
  __shared__ __align__(16) u16 Vs[2][32][64];    // [buf][d][key] fp16 (8KB)
  const int tid = threadIdx.x, wid = tid >> 6, lane = tid & 63;
  const int lm = lane & 15, quad = lane >> 4;
  const int bid = blockIdx.x;

  if (WMLP && bid < 16) {        // ---- Wmlp tile (aliases Ks/Vs as As/Bs) ----
    const float probe = bf2f(((const u16*)fc2_w)[lane]);
    const bool f32 = __ballot(!(fabsf(probe) < 1000.0f)) != 0ull;
    #define RDW(p, i) (f32 ? ((const float*)(p))[i] : bf2f(((const u16*)(p))[i]))
    u16 (*As)[40] = (u16(*)[40])&Ks[0][0][0];    // 2560 u16 <= 4096 avail
    u16 (*Bs)[40] = (u16(*)[40])&Vs[0][0][0];
    const int tn = bid >> 2, tk2 = bid & 3;
    const int n0v = tn * 64, k0v = tk2 * 64;
    const int wm = (wid >> 1) * 32, wn = (wid & 1) * 32;
    floatx4 zero = {0.f, 0.f, 0.f, 0.f};
    floatx4 acc[2][2] = {{zero, zero}, {zero, zero}};
    const int an = tid & 63, aj8 = (tid >> 6) * 8;   // A: col-owner n, j-octet
    const int bk = tid >> 2, bj8 = (tid & 3) * 8;    // B: row k, 8 j each
    short8 ra, rb;
    auto ld = [&](int j0) {
#pragma unroll
      for (int jj = 0; jj < 8; ++jj)
        ra[jj] = (short)f2h(RDW(fc2_w, (size_t)(j0 + aj8 + jj) * 256 + n0v + an));
      if (f32) {
        const float* bp = (const float*)fc1_w + (size_t)(k0v + bk) * 1024 + j0 + bj8;
        floatx4 b0 = *(const floatx4*)bp;
        floatx4 b1 = *(const floatx4*)(bp + 4);
#pragma unroll
        for (int jj = 0; jj < 4; ++jj) {
          rb[jj]     = (short)f2h(b0[jj]);
          rb[4 + jj] = (short)f2h(b1[jj]);
        }
      } else {
        short8 bbv = *(const short8*)((const u16*)fc1_w +
                                      (size_t)(k0v + bk) * 1024 + j0 + bj8);
#pragma unroll
        for (int jj = 0; jj < 8; ++jj) rb[jj] = (short)f2h(bf2f((u16)bbv[jj]));
      }
    };
    ld(0);
    for (int j0 = 0; j0 < 1024; j0 += 32) {
      if (j0) __syncthreads();
      *(short8*)&As[an][aj8] = ra;
      *(short8*)&Bs[bk][bj8] = rb;
      __syncthreads();
      if (j0 + 32 < 1024) ld(j0 + 32);
      half8 fa[2], fb[2];
#pragma unroll
      for (int t = 0; t < 2; ++t) {
        fa[t] = *(const half8*)&As[wm + t * 16 + lm][quad * 8];
        fb[t] = *(const half8*)&Bs[wn + t * 16 + lm][quad * 8];
      }
#pragma unroll
      for (int i = 0; i < 2; ++i)
#pragma unroll
        for (int j = 0; j < 2; ++j)
          acc[i][j] = MFMAG(fa[i], fb[j], acc[i][j]);
    }
#pragma unroll
    for (int i = 0; i < 2; ++i) {
      const int rown = n0v + wm + i * 16 + quad * 4;
#pragma unroll
      for (int j = 0; j < 2; ++j) {
        const int colk = k0v + wn + j * 16 + lm;
#pragma unroll
        for (int r = 0; r < 4; ++r)
          wmlp[(size_t)(rown + r) * 256 + colk] = f2h(acc[i][j][r]);
      }
    }
    #undef RDW
    return;
  }

  const int abid = WMLP ? bid - 16 : bid;
  const int chunk = (CHUNKS > 1) ? (abid >> 9) : 0;
  const int qblk = abid & 31, bh = (abid >> 5) & 15;
  const int b = bh >> 3, h = bh & 7;
  const int q0 = qblk * 64 + wid * 16;
  const size_t tb = (size_t)b * 2048;
  const int NT = 32 / CHUNKS;
  const int kofs = chunk * (2048 / CHUNKS);

  half8 qh;
  { size_t off = (tb + q0 + lm) * 256 + h * 32 + quad * 8;
    qh = *(const half8*)&qf16[off]; }

  const int kkey = tid >> 2, kg = tid & 3;
  const size_t kb = (tb + kofs + kkey) * 256 + h * 32 + kg * 8;
  const int vd = tid >> 3, vp = tid & 7, vk8 = vp ^ (vd & 7);
  const size_t vb = (size_t)(bh * 32 + vd) * 2048 + kofs + vk8 * 8;

  gll16(kf16 + kb, (u16*)Ks + tid * 8);
  gll16(vt  + vb,  (u16*)Vs + tid * 8);

  float mrun = -1e30f, lrun = 0.f;
  floatx4 o0 = {0.f,0.f,0.f,0.f}, o1 = {0.f,0.f,0.f,0.f};

  for (int kt = 0; kt < NT; ++kt) {
    const int buf = kt & 1;
    __syncthreads();
    if (kt < NT - 1) {
      const int nb = (buf ^ 1) * 2048;
      const size_t ko = (size_t)(kt + 1) * 16384;
      const size_t vo = (size_t)(kt + 1) * 64;
      gll16(kf16 + kb + ko, (u16*)Ks + nb + tid * 8);
      gll16(vt  + vb + vo,  (u16*)Vs + nb + tid * 8);
    }

    floatx4 z[4];
#pragma unroll
    for (int kf = 0; kf < 4; ++kf) {
      half8 khf = *(const half8*)&Ks[buf][kf * 16 + lm][quad * 8];
      floatx4 zz = {0.f,0.f,0.f,0.f};
      z[kf] = MFMAG(khf, qh, zz);
    }
    float zm = fmaxf(fmaxf(fmaxf(z[0][0], z[0][1]), fmaxf(z[0][2], z[0][3])),
               fmaxf(fmaxf(z[1][0], z[1][1]), fmaxf(z[1][2], z[1][3])));
    zm = fmaxf(zm, fmaxf(fmaxf(fmaxf(z[2][0], z[2][1]), fmaxf(z[2][2], z[2][3])),
                   fmaxf(fmaxf(z[3][0], z[3][1]), fmaxf(z[3][2], z[3][3]))));
    zm = fmaxf(zm, __shfl_xor(zm, 16));
    zm = fmaxf(zm, __shfl_xor(zm, 32));
    const float mn = fmaxf(mrun, zm);
    const float alpha = EX2((mrun - mn) * CLF);
    const float mc = mn * CLF;
    mrun = mn;
    float ls = 0.f;
    half4 pb[4];
#pragma unroll
    for (int kf = 0; kf < 4; ++kf) {
      const float p0 = EX2(__builtin_fmaf(z[kf][0], CLF, -mc));
      const float p1 = EX2(__builtin_fmaf(z[kf][1], CLF, -mc));
      const float p2 = EX2(__builtin_fmaf(z[kf][2], CLF, -mc));
      const float p3 = EX2(__builtin_fmaf(z[kf][3], CLF, -mc));
      ls += (p0 + p1) + (p2 + p3);
      uint2v uu = {pkh2(p0, p1), pkh2(p2, p3)};
      pb[kf] = *(half4*)&uu;
    }
    ls += __shfl_xor(ls, 16);
    ls += __shfl_xor(ls, 32);
    lrun = lrun * alpha + ls;
#pragma unroll
    for (int r = 0; r < 4; ++r) { o0[r] *= alpha; o1[r] *= alpha; }
    const u16* vbase = (const u16*)Vs + buf * 2048;
#pragma unroll
    for (int kf = 0; kf < 4; ++kf) {
      const int k8 = 2 * kf + (quad >> 1);
      const int d0 = lm, d1 = 16 + lm;
      half4 vf0 = *(const half4*)(vbase + (d0 * 8 + (k8 ^ (d0 & 7))) * 8 + (quad & 1) * 4);
      half4 vf1 = *(const half4*)(vbase + (d1 * 8 + (k8 ^ (d1 & 7))) * 8 + (quad & 1) * 4);
      o0 = MFMAPV(vf0, pb[kf], o0);
      o1 = MFMAPV(vf1, pb[kf], o1);
    }
  }
  const float inv = 1.0f / lrun;
  const size_t tok = tb + q0 + lm;
  u16* dst = ((CHUNKS > 2 && chunk >= 2) ? out23 : outp) + (size_t)(chunk & 1) * 1048576;
  const size_t rowo = tok * 256 + h * 32;
#pragma unroll
  for (int r = 0; r < 4; ++r) {
    dst[rowo + quad * 4 + r]      = f2h(o0[r] * inv);
    dst[rowo + 16 + quad * 4 + r] = f2h(o1[r] * inv);
  }
  if (CHUNKS > 1 && quad == 0)
    mu[chunk * 32768 + tok * 8 + h] = __builtin_fmaf(mrun, CLF, __log2f(lrun));
}

// ---------------- combine (fallback, sk2 path only) ----------------
template<int CHUNKS>
__global__ __launch_bounds__(256) void combine_k(u16* __restrict__ d,
                                                 const u16* __restrict__ e,
                                                 const float* __restrict__ mu)
{
  const int t = blockIdx.x, c = threadIdx.x, h = c >> 5;
  const size_t o = (size_t)t * 256 + c;
  float m[CHUNKS];
  float M = -1e30f;
#pragma unroll
  for (int i = 0; i < CHUNKS; ++i) { m[i] = mu[i * 32768 + t * 8 + h]; M = fmaxf(M, m[i]); }
  float wsum = 0.f, acc = 0.f;
#pragma unroll
  for (int i = 0; i < CHUNKS; ++i) {
    const float w = EX2(m[i] - M);
    const u16 v = (i < 2) ? d[o + (size_t)i * 1048576] : e[o + (size_t)(i - 2) * 1048576];
    wsum += w; acc += w * h2f(v);
  }
  d[o] = f2h(acc / wsum);
}

// ---------------- residual add + LayerNorm (fallback paths only) ----------------
__global__ __launch_bounds__(256) void ln_k(const float* __restrict__ pf,
                                            const u16* __restrict__ xh,
                                            const u16* __restrict__ g,
                                            const u16* __restrict__ bta,
                                            u16* __restrict__ net)
{
  const int t = blockIdx.x, c = threadIdx.x;
  const size_t o = (size_t)t * 256 + c;
  float v = pf[o] + h2f(xh[o]);
  float s = v, s2 = v * v;
#pragma unroll
  for (int d = 1; d < 64; d <<= 1) { s += __shfl_xor(s, d); s2 += __shfl_xor(s2, d); }
  __shared__ float ss[4], ss2[4];
  const int w = c >> 6;
  if ((c & 63) == 0) { ss[w] = s; ss2[w] = s2; }
  __syncthreads();
  s = ss[0] + ss[1] + ss[2] + ss[3];
  s2 = ss2[0] + ss2[1] + ss2[2] + ss2[3];
  const float mu = s * (1.f / 256.f);
  const float var = s2 * (1.f / 256.f) - mu * mu;
  const float is = rsqrtf(var + 1e-5f);
  net[o] = f2h((v - mu) * is * h2f(g[c]) + h2f(bta[c]));
}

extern "C" void kernel_launch(void* const* d_in, const int* in_sizes, int n_in,
                              void* d_out, int out_size, void* d_ws, size_t ws_size,
                              hipStream_t stream) {
  const void* x      = d_in[0];
  const void* qkv_w  = d_in[1];
  const void* proj_w = d_in[2];
  const void* proj_b = d_in[3];
  const void* fc1_w  = d_in[4];
  const void* fc1_b  = d_in[5];
  const void* fc2_w  = d_in[6];
  const void* fc2_b  = d_in[7];
  const void* ln_g   = d_in[8];
  const void* ln_b   = d_in[9];

  char* ws = (char*)d_ws;
  u16* b_proj  = (u16*)(ws + 4096);
  u16* b_fc1   = (u16*)(ws + 8192);
  u16* bmlp    = (u16*)(ws + 12288);     // sk4: bmlp; fallback: b_fc2
  u16* b_fc2   = (u16*)(ws + 12288);
  u16* g_ln    = (u16*)(ws + 16384);
  u16* bb_ln   = (u16*)(ws + 20480);
  u16* wq_f    = (u16*)(ws + 131072);    // fallback only
  u16* wt_proj = (u16*)(ws + 524288);
  u16* wt_fc1  = (u16*)(ws + 655360);    // fallback only
  u16* wt_fc2  = (u16*)(ws + 1179648);   // fallback only
  u16* wmlp    = (u16*)(ws + 1703936);   // sk4: [256 n][256 k] fp16, 128KB
  u16* x_f     = (u16*)(ws + 2097152);   // fallback only
  u16* q_f16   = (u16*)(ws + 4194304);
  u16* k_f16   = (u16*)(ws + 6291456);
  u16* vt      = (u16*)(ws + 8388608);
  float* mu    = (float*)(ws + 10485760);
  u16* out23   = (u16*)(ws + 11010048);
  u16* attn    = (u16*)d_out;            // chunks 0,1 (d_out scratch until mlp)

  // sk4 path: net over the (unused) x_f region
  u16* net4    = (u16*)(ws + 2097152);

  // fallback-path buffers
  float* projf = (float*)(ws + 4194304);
  u16* net     = (u16*)(ws + 11010048);
  u16* hbuf    = (u16*)(ws + 2097152);

  const bool sk4 = ws_size >= 15204352;    // call-invariant -> graph-safe
  const bool sk2 = ws_size >= 11010048;

  if (sk4) {
    // 1) qkv GEMM from raw inputs + proj transpose + bmlp + params
    qkvprep_k<<<789, 256, 0, stream>>>(x, qkv_w, proj_w, proj_b,
                                       fc1_b, fc2_w, fc2_b, ln_g, ln_b,
                                       wt_proj, bmlp, b_proj, g_ln, bb_ln,
                                       vt, q_f16, k_f16);
    // 2) attention (4-way split-K) + 16 Wmlp tiles at bids 0..15
    attn_k<4, true><<<2064, 256, 0, stream>>>(q_f16, k_f16, vt, attn, out23, mu,
                                              fc1_w, fc2_w, wmlp);
    // 3) proj + combine + bias + residual(raw x) + LN -> net fp16
    projln8_k<<<256, 512, 0, stream>>>(attn, out23, wt_proj, b_proj, x, qkv_w,
                                       g_ln, bb_ln, mu, net4);
    // 4) collapsed MLP: out = net @ Wmlp + bmlp + net -> d_out fp32
    gemm_k<2, 0, true, true, false><<<dim3(4, 64), 256, 0, stream>>>(
        net4, wmlp, nullptr, bmlp, net4, d_out, nullptr, nullptr, nullptr,
        4096, 256, 256);
    return;
  }

  prep_k<<<1224, 256, 0, stream>>>(x, qkv_w, proj_w, fc1_w, fc2_w,
                                   proj_b, fc1_b, fc2_b, ln_g, ln_b,
                                   x_f, wq_f, wt_proj, wt_fc1, wt_fc2,
                                   b_proj, b_fc1, b_fc2, g_ln, bb_ln);
  gemm_k<2, 2, false, false, false><<<dim3(12, 64), 256, 0, stream>>>(
      x_f, wq_f, nullptr, nullptr, nullptr, vt, q_f16, k_f16, nullptr, 4096, 768, 256);
  if (sk2) {
    attn_k<2, false><<<1024, 256, 0, stream>>>(q_f16, k_f16, vt, attn, nullptr, mu,
                                               nullptr, nullptr, nullptr);
    combine_k<2><<<4096, 256, 0, stream>>>(attn, nullptr, mu);
    gemm_k<2, 0, true, false, false><<<dim3(4, 64), 256, 0, stream>>>(
        attn, wt_proj, nullptr, b_proj, nullptr, projf, nullptr, nullptr, nullptr,
        4096, 256, 256);
  } else {
    attn_k<1, false><<<512, 256, 0, stream>>>(q_f16, k_f16, vt, attn, nullptr, nullptr,
                                              nullptr, nullptr, nullptr);
    gemm_k<2, 0, true, false, false><<<dim3(4, 64), 256, 0, stream>>>(
        attn, wt_proj, nullptr, b_proj, nullptr, projf, nullptr, nullptr, nullptr,
        4096, 256, 256);
  }
  ln_k<<<4096, 256, 0, stream>>>(projf, x_f, g_ln, bb_ln, net);
  gemm_k<2, 1, true, false, false><<<dim3(16, 64), 256, 0, stream>>>(
      net, wt_fc1, nullptr, b_fc1, nullptr, hbuf, nullptr, nullptr, nullptr,
      4096, 1024, 256);
  gemm_k<2, 0, true, true, false><<<dim3(4, 64), 256, 0, stream>>>(
      hbuf, wt_fc2, nullptr, b_fc2, net, d_out, nullptr, nullptr, nullptr,
      4096, 256, 1024);
}

// Round 13
// 145.872 us; speedup vs baseline: 1.0241x; 1.0241x over previous
//
#include <hip/hip_runtime.h>

// B=2,N=2048,D=256,H=8,HD=32,DFF=1024. SCALE MULTIPLIES by sqrt(32). No MLP
// activation. Post-norm. Inputs fp32 (auto-detected), output fp32.
// R24: 141.2us. R25/R26/R27: MLP-collapse attempts 169.6/144.7/149.4 — a
// K=1024 Wmlp tile is a ~15-20us SERIAL pole; it can't hide anywhere.
//
// R28: split-K Wmlp. 64 blocks (16 tiles x 4 j-chunks of 256, 16 phases each
// ~4-5us) ride in the attn dispatch writing fp32 partials to wpart[4][256][256].
// 4 reducer blocks in the projln8 dispatch fold partials -> wmlp fp16 (done
// well before the mlp GEMM). Pole is 4x shorter -> genuinely hideable.
// 4 dispatches. sk4 gate 16252928 (wpart 1MB after out23).

typedef __attribute__((ext_vector_type(8))) short short8;       // raw 16B
typedef __attribute__((ext_vector_type(4))) short short4v;      // raw 8B
typedef __attribute__((ext_vector_type(8))) _Float16 half8;     // 8 fp16 = 4 VGPRs
typedef __attribute__((ext_vector_type(4))) _Float16 half4;     // 4 fp16 = 2 VGPRs
typedef __attribute__((ext_vector_type(2))) __fp16 fp16x2;      // cvt_pkrtz return type
typedef __attribute__((ext_vector_type(4))) float floatx4;
typedef __attribute__((ext_vector_type(2))) unsigned int uint2v;
typedef unsigned short u16;

#define MFMAG(a,b,c)  __builtin_amdgcn_mfma_f32_16x16x32_f16((a),(b),(c),0,0,0)
#if __has_builtin(__builtin_amdgcn_mfma_f32_16x16x16_f16)
#define MFMAPV(a,b,c) __builtin_amdgcn_mfma_f32_16x16x16_f16((a),(b),(c),0,0,0)
#else
#define MFMAPV(a,b,c) __builtin_amdgcn_mfma_f32_16x16x16f16((a),(b),(c),0,0,0)
#endif
#define CLF 8.1615404f   // SCALE * log2(e)

#if __has_builtin(__builtin_amdgcn_exp2f)
#define EX2(x) __builtin_amdgcn_exp2f(x)
#else
#define EX2(x) exp2f(x)
#endif

__device__ __forceinline__ float bf2f(u16 u) { return __uint_as_float(((unsigned)u) << 16); }
__device__ __forceinline__ float h2f(u16 u) { _Float16 h = *(_Float16*)&u; return (float)h; }
__device__ __forceinline__ u16 f2h(float f) { _Float16 h = (_Float16)f; return *(u16*)&h; }
// pack 2 fp32 -> 2 fp16 (RTZ), 1 VALU
__device__ __forceinline__ unsigned pkh2(float a, float b) {
#if __has_builtin(__builtin_amdgcn_cvt_pkrtz)
  fp16x2 h = __builtin_amdgcn_cvt_pkrtz(a, b);
  return *(unsigned*)&h;
#else
  return (unsigned)f2h(a) | ((unsigned)f2h(b) << 16);
#endif
}
// async global->LDS, 16B/lane; LDS dest = wave-uniform base + lane*16 (m104)
__device__ __forceinline__ void gll16(const void* g, void* l) {
  __builtin_amdgcn_global_load_lds((const __attribute__((address_space(1))) void*)g,
                                   (__attribute__((address_space(3))) void*)l, 16, 0, 0);
}

// ---------------- fused qkv GEMM + proj-transpose + bmlp + params ------------
// Grid 789 x 256 thr. bid<16: proj_w transpose; 16..19: bmlp quarters; 20: params.
// bid>=21: qkv 64x64 tile (qbid=bid-21), A=x raw, B=qkv_w raw transposed-in-
// staging; epilogue Q->qf, K->kf, V->vt.
__global__ __launch_bounds__(256) void qkvprep_k(
    const void* __restrict__ x, const void* __restrict__ qkv_w,
    const void* __restrict__ proj_w, const void* __restrict__ proj_b,
    const void* __restrict__ fc1_b, const void* __restrict__ fc2_w,
    const void* __restrict__ fc2_b,
    const void* __restrict__ ln_g, const void* __restrict__ ln_b,
    u16* __restrict__ wt_proj, u16* __restrict__ bmlp,
    u16* __restrict__ b_proj, u16* __restrict__ g_ln, u16* __restrict__ bb_ln,
    u16* __restrict__ vt, u16* __restrict__ qf, u16* __restrict__ kf)
{
  __shared__ __align__(16) u16 lds[9728];   // As(2560)|Bs(2560)|Vt(4608); tr aliases
  const int tid = threadIdx.x;
  const int lane = tid & 63;
  const float probe = bf2f(((const u16*)qkv_w)[lane]);
  const bool f32 = __ballot(!(fabsf(probe) < 1000.0f)) != 0ull;
  const int bid = blockIdx.x;
  #define RD(p, i) (f32 ? ((const float*)(p))[i] : bf2f(((const u16*)(p))[i]))

  if (bid < 21) {
    int idx = bid;
    if (idx < 16) {               // ---- proj_w transpose tiles ----
      u16 (*tr)[70] = (u16(*)[70])lds;
      const int tk = idx & 3, tn = idx >> 2;
      const int k0 = tk * 64, n0v = tn * 64;
      const int r = tid >> 6, c = tid & 63;
#pragma unroll
      for (int p = 0; p < 16; ++p) {
        const int k = k0 + p * 4 + r;
        tr[c][p * 4 + r] = f2h(RD(proj_w, (size_t)k * 256 + n0v + c));
      }
      __syncthreads();
#pragma unroll
      for (int p = 0; p < 16; ++p) {
        const int n = n0v + p * 4 + r;
        wt_proj[(size_t)n * 256 + k0 + c] = tr[p * 4 + r][c];
      }
    } else if (idx < 20) {        // ---- bmlp quarter ----
      const int q = idx - 16;
      const int n = q * 64 + (tid >> 2), jg = tid & 3;
      float s = 0.f;
#pragma unroll 8
      for (int j = jg; j < 1024; j += 4)
        s += RD(fc1_b, j) * RD(fc2_w, (size_t)j * 256 + n);
      s += __shfl_xor(s, 1);
      s += __shfl_xor(s, 2);
      if (jg == 0) bmlp[n] = f2h(s + RD(fc2_b, n));
    } else {                      // ---- small fp16 params ----
      b_proj[tid] = f2h(RD(proj_b, tid));
      g_ln[tid]   = f2h(RD(ln_g, tid));
      bb_ln[tid]  = f2h(RD(ln_b, tid));
    }
    return;
  }

  // ---- qkv GEMM path ----
  u16 (*As)[40] = (u16(*)[40])lds;
  u16 (*Bs)[40] = (u16(*)[40])(lds + 2560);
  u16* Vt = lds + 5120;
  const int qbid = bid - 21;
  const int mb = qbid / 12, nb = qbid % 12;
  const int m0 = mb * 64, n0 = nb * 64;
  const int wid = tid >> 6;
  const int wm = (wid >> 1) * 32, wn = (wid & 1) * 32;
  const int lm = lane & 15, quad = lane >> 4;

  floatx4 zero = {0.f, 0.f, 0.f, 0.f};
  floatx4 acc[2][2] = {{zero, zero}, {zero, zero}};

  const int arow = tid >> 2, aoff = (tid & 3) * 8;
  const int bn = tid & 63, bk8 = (tid >> 6) * 8;

  short8 rah, rbh;
  auto ld = [&](int kk) {
    if (f32) {
      const float* xp = (const float*)x + (size_t)(m0 + arow) * 256 + kk + aoff;
      floatx4 a0 = *(const floatx4*)xp;
      floatx4 a1 = *(const floatx4*)(xp + 4);
#pragma unroll
      for (int j = 0; j < 4; ++j) {
        rah[j]     = (short)f2h(a0[j]);
        rah[4 + j] = (short)f2h(a1[j]);
      }
      const float* wp = (const float*)qkv_w + (size_t)(kk + bk8) * 768 + n0 + bn;
#pragma unroll
      for (int j = 0; j < 8; ++j) rbh[j] = (short)f2h(wp[(size_t)j * 768]);
    } else {
      short8 a = *(const short8*)((const u16*)x + (size_t)(m0 + arow) * 256 + kk + aoff);
#pragma unroll
      for (int j = 0; j < 8; ++j) rah[j] = (short)f2h(bf2f((u16)a[j]));
      const u16* wp = (const u16*)qkv_w + (size_t)(kk + bk8) * 768 + n0 + bn;
#pragma unroll
      for (int j = 0; j < 8; ++j) rbh[j] = (short)f2h(bf2f(wp[(size_t)j * 768]));
    }
  };
  ld(0);
  for (int k0 = 0; k0 < 256; k0 += 32) {
    if (k0) __syncthreads();
    *(short8*)&As[arow][aoff] = rah;
    *(short8*)&Bs[bn][bk8] = rbh;
    __syncthreads();
    if (k0 + 32 < 256) ld(k0 + 32);     // next-tile loads fly during MFMAs
    half8 fa[2], fb[2];
#pragma unroll
    for (int t = 0; t < 2; ++t) {
      fa[t] = *(const half8*)&As[wm + t * 16 + lm][quad * 8];
      fb[t] = *(const half8*)&Bs[wn + t * 16 + lm][quad * 8];
    }
#pragma unroll
    for (int i = 0; i < 2; ++i)
#pragma unroll
      for (int j = 0; j < 2; ++j)
        acc[i][j] = MFMAG(fa[i], fb[j], acc[i][j]);
  }
  #undef RD

  // ---- V epilogue (n0>=512) ----
  if (n0 >= 512) {
    __syncthreads();
#pragma unroll
    for (int i = 0; i < 2; ++i)
#pragma unroll
      for (int j = 0; j < 2; ++j)
#pragma unroll
        for (int r = 0; r < 4; ++r)
          Vt[(wn + j * 16 + lm) * 72 + wm + i * 16 + quad * 4 + r] = f2h(acc[i][j][r]);
    __syncthreads();
    const int bb = m0 >> 11, n = m0 & 2047;
#pragma unroll
    for (int pass = 0; pass < 2; ++pass) {
      const int dl = (tid >> 3) + pass * 32;
      const int oct = tid & 7;
      const int col = n0 - 512 + dl;
      const int d = col & 31, hh = col >> 5;
      short8 v = *(const short8*)&Vt[dl * 72 + oct * 8];
      *(short8*)&vt[(size_t)((bb * 8 + hh) * 32 + d) * 2048 + n + oct * 8] = v;
    }
    return;
  }

  // ---- Q/K epilogue ----
#pragma unroll
  for (int i = 0; i < 2; ++i) {
    const int rowb = m0 + wm + i * 16 + quad * 4;
#pragma unroll
    for (int j = 0; j < 2; ++j) {
      const int col = n0 + wn + j * 16 + lm;
#pragma unroll
      for (int r = 0; r < 4; ++r) {
        const int row = rowb + r;
        const u16 hv = f2h(acc[i][j][r]);
        if (col < 256) qf[(size_t)row * 256 + col] = hv;
        else           kf[(size_t)row * 256 + (col - 256)] = hv;
      }
    }
  }
}

// ---------------- prep (FALLBACK paths only) ----------------
__global__ __launch_bounds__(256) void prep_k(
    const void* __restrict__ x, const void* __restrict__ qkv_w,
    const void* __restrict__ proj_w, const void* __restrict__ fc1_w,
    const void* __restrict__ fc2_w, const void* __restrict__ proj_b,
    const void* __restrict__ fc1_b, const void* __restrict__ fc2_b,
    const void* __restrict__ ln_g, const void* __restrict__ ln_b,
    u16* __restrict__ x_f, u16* __restrict__ wq_f,
    u16* __restrict__ wt_proj, u16* __restrict__ wt_fc1, u16* __restrict__ wt_fc2,
    u16* __restrict__ b_proj, u16* __restrict__ b_fc1, u16* __restrict__ b_fc2,
    u16* __restrict__ g_ln, u16* __restrict__ bb_ln)
{
  __shared__ u16 tr[64][70];
  const int lane = threadIdx.x & 63;
  const float probe = bf2f(((const u16*)qkv_w)[lane]);
  const bool f32 = __ballot(!(fabsf(probe) < 1000.0f)) != 0ull;
  const int bid = blockIdx.x, tid = threadIdx.x;
  #define RD(p, i) (f32 ? ((const float*)(p))[i] : bf2f(((const u16*)(p))[i]))
  if (bid < 1024) {
    const size_t i = (size_t)bid * 1024 + tid * 4;
    const u16 o0 = f2h(RD(x, i)),     o1 = f2h(RD(x, i + 1));
    const u16 o2 = f2h(RD(x, i + 2)), o3 = f2h(RD(x, i + 3));
    short4v sv = {(short)o0, (short)o1, (short)o2, (short)o3};
    *(short4v*)&x_f[i] = sv;
  } else if (bid < 1216) {
    int idx = bid - 1024;
    const void* src; u16* dst; int Ns, Kt, tk, tn;
    if (idx < 48)       { src = qkv_w;  dst = wq_f;    Ns = 768;  Kt = 256;
                          tk = idx & 3;  tn = idx >> 2; }
    else if (idx < 64)  { idx -= 48;  src = proj_w; dst = wt_proj; Ns = 256; Kt = 256;
                          tk = idx & 3;  tn = idx >> 2; }
    else if (idx < 128) { idx -= 64;  src = fc1_w;  dst = wt_fc1;  Ns = 1024; Kt = 256;
                          tk = idx & 3;  tn = idx >> 2; }
    else                { idx -= 128; src = fc2_w;  dst = wt_fc2;  Ns = 256;  Kt = 1024;
                          tk = idx & 15; tn = idx >> 4; }
    const int k0 = tk * 64, n0 = tn * 64;
    const int r = tid >> 6, c = tid & 63;
#pragma unroll
    for (int p = 0; p < 16; ++p) {
      const int k = k0 + p * 4 + r;
      tr[c][p * 4 + r] = f2h(RD(src, (size_t)k * Ns + n0 + c));
    }
    __syncthreads();
#pragma unroll
    for (int p = 0; p < 16; ++p) {
      const int n = n0 + p * 4 + r;
      dst[(size_t)n * Kt + k0 + c] = tr[p * 4 + r][c];
    }
  } else {
    const int j = (bid - 1216) * 256 + tid;
    if (j < 256)       b_proj[j]        = f2h(RD(proj_b, j));
    else if (j < 1280) b_fc1[j - 256]   = f2h(RD(fc1_b, j - 256));
    else if (j < 1536) b_fc2[j - 1280]  = f2h(RD(fc2_b, j - 1280));
    else if (j < 1792) g_ln[j - 1536]   = f2h(RD(ln_g, j - 1536));
    else if (j < 2048) bb_ln[j - 1792]  = f2h(RD(ln_b, j - 1792));
  }
  #undef RD
}

// ---------------- GEMM (fp16, fp32 accum) with register-prefetch staging ----------------
template<int TW, int EPI, bool BIAS, bool RES, bool COMB>
__global__ __launch_bounds__(256) void gemm_k(
    const u16* __restrict__ A, const u16* __restrict__ Bt, const u16* __restrict__ A2,
    const u16* __restrict__ bias, const u16* __restrict__ res,
    void* __restrict__ out0, u16* __restrict__ aux1, u16* __restrict__ aux3,
    const float* __restrict__ muc,
    int M, int Nn, int K)
{
  constexpr int BT = TW * 32;
  constexpr int NC = TW / 2;
  __shared__ __align__(16) u16 As[BT][40];
  __shared__ __align__(16) u16 Bs[BT][40];
  __shared__ __align__(16) u16 Vt[(EPI == 2) ? 64 * 72 : 1];
  const int tid = threadIdx.x;
  const int m0 = blockIdx.y * BT, n0 = blockIdx.x * BT;
  const int wid = tid >> 6, lane = tid & 63;
  const int wm = (wid >> 1) * (TW * 16), wn = (wid & 1) * (TW * 16);
  const int lm = lane & 15, quad = lane >> 4;

  floatx4 zero = {0.f, 0.f, 0.f, 0.f};
  floatx4 acc[TW][TW];
#pragma unroll
  for (int i = 0; i < TW; ++i)
#pragma unroll
    for (int j = 0; j < TW; ++j) acc[i][j] = zero;

  auto comb8 = [&](int t, int col8) -> short8 {
    const size_t o = (size_t)t * 256 + col8;
    const int h = col8 >> 5;
    const float m0_ = muc[t * 8 + h],          m1_ = muc[32768 + t * 8 + h];
    const float m2_ = muc[65536 + t * 8 + h],  m3_ = muc[98304 + t * 8 + h];
    const float M = fmaxf(fmaxf(m0_, m1_), fmaxf(m2_, m3_));
    float w0 = EX2(m0_ - M), w1 = EX2(m1_ - M), w2 = EX2(m2_ - M), w3 = EX2(m3_ - M);
    const float inv = 1.f / (w0 + w1 + w2 + w3);
    w0 *= inv; w1 *= inv; w2 *= inv; w3 *= inv;
    short8 a0 = *(const short8*)&A[o],  a1 = *(const short8*)&A[o + 1048576];
    short8 a2 = *(const short8*)&A2[o], a3 = *(const short8*)&A2[o + 1048576];
    float v[8];
#pragma unroll
    for (int j = 0; j < 8; ++j)
      v[j] = w0 * h2f((u16)a0[j]) + w1 * h2f((u16)a1[j])
           + w2 * h2f((u16)a2[j]) + w3 * h2f((u16)a3[j]);
    uint2v uu0 = {pkh2(v[0], v[1]), pkh2(v[2], v[3])};
    uint2v uu1 = {pkh2(v[4], v[5]), pkh2(v[6], v[7])};
    short8 r;
    *(uint2v*)&r = uu0; *((uint2v*)&r + 1) = uu1;
    return r;
  };

  int srow[NC], soff[NC];
#pragma unroll
  for (int c = 0; c < NC; ++c) {
    const int cid = tid * NC + c;
    srow[c] = cid >> 2; soff[c] = (cid & 3) * 8;
  }

  short8 ra0[NC], rb0[NC];
  auto ld = [&](int kk) {
#pragma unroll
    for (int c = 0; c < NC; ++c) {
      rb0[c] = *(const short8*)&Bt[(size_t)(n0 + srow[c]) * K + kk + soff[c]];
      if (COMB) ra0[c] = comb8(m0 + srow[c], kk + soff[c]);
      else      ra0[c] = *(const short8*)&A[(size_t)(m0 + srow[c]) * K + kk + soff[c]];
    }
  };
  ld(0);
  for (int k0 = 0; k0 < K; k0 += 32) {
    if (k0) __syncthreads();
#pragma unroll
    for (int c = 0; c < NC; ++c) {
      *(short8*)&As[srow[c]][soff[c]] = ra0[c];
      *(short8*)&Bs[srow[c]][soff[c]] = rb0[c];
    }
    __syncthreads();
    if (k0 + 32 < K) ld(k0 + 32);
    half8 fa[TW], fb[TW];
#pragma unroll
    for (int t = 0; t < TW; ++t) {
      fa[t] = *(const half8*)&As[wm + t * 16 + lm][quad * 8];
      fb[t] = *(const half8*)&Bs[wn + t * 16 + lm][quad * 8];
    }
#pragma unroll
    for (int i = 0; i < TW; ++i)
#pragma unroll
      for (int j = 0; j < TW; ++j)
        acc[i][j] = MFMAG(fa[i], fb[j], acc[i][j]);
  }

  if (EPI == 2 && n0 >= 512) {
    __syncthreads();
#pragma unroll
    for (int i = 0; i < TW; ++i)
#pragma unroll
      for (int j = 0; j < TW; ++j)
#pragma unroll
        for (int r = 0; r < 4; ++r)
          Vt[(wn + j * 16 + lm) * 72 + wm + i * 16 + quad * 4 + r] = f2h(acc[i][j][r]);
    __syncthreads();
    const int bb = m0 >> 11, n = m0 & 2047;
#pragma unroll
    for (int pass = 0; pass < 2; ++pass) {
      const int dl = (tid >> 3) + pass * 32;
      const int oct = tid & 7;
      const int col = n0 - 512 + dl;
      const int d = col & 31, hh = col >> 5;
      short8 v = *(const short8*)&Vt[dl * 72 + oct * 8];
      *(short8*)&((u16*)out0)[(size_t)((bb * 8 + hh) * 32 + d) * 2048 + n + oct * 8] = v;
    }
    return;
  }

#pragma unroll
  for (int i = 0; i < TW; ++i) {
    const int rowb = m0 + wm + i * 16 + quad * 4;
#pragma unroll
    for (int j = 0; j < TW; ++j) {
      const int col = n0 + wn + j * 16 + lm;
      const float bv = BIAS ? h2f(bias[col]) : 0.f;
#pragma unroll
      for (int r = 0; r < 4; ++r) {
        const int row = rowb + r;
        float v = acc[i][j][r] + bv;
        const size_t o = (size_t)row * Nn + col;
        if (RES) v += h2f(res[o]);
        if (EPI == 0) {
          ((float*)out0)[o] = v;
        } else if (EPI == 1) {
          ((u16*)out0)[o] = f2h(v);
        } else {
          if (col < 256) aux1[(size_t)row * 256 + col] = f2h(v);
          else           aux3[(size_t)row * 256 + (col - 256)] = f2h(v);
        }
      }
    }
  }
}

// ---------------- fused proj + combine + bias + residual(raw x) + LN (8 waves) ----
// RED=true: bids 0..3 reduce wpart (4x fp32) -> wmlp fp16; projln at bid-4.
template<bool RED>
__global__ __launch_bounds__(512) void projln8_k(
    const u16* __restrict__ A,      // attn chunks 0,1
    const u16* __restrict__ A2,     // attn chunks 2,3
    const u16* __restrict__ Bt,     // wt_proj [256 n][256 k] fp16
    const u16* __restrict__ bias,   // b_proj fp16
    const void* __restrict__ xraw,  // raw x (fp32 or bf16)
    const void* __restrict__ probew,// qkv_w for dtype probe
    const u16* __restrict__ g, const u16* __restrict__ bb,
    const float* __restrict__ muc,
    u16* __restrict__ net,
    const float* __restrict__ wpart, u16* __restrict__ wmlp)
{
  __shared__ __align__(16) u16 As[16][40];
  __shared__ __align__(16) u16 Bs[256][40];
  __shared__ float ss[8][16], ssq[8][16];
  const int tid = threadIdx.x;
  const int bid = blockIdx.x;

  if (RED && bid < 4) {           // ---- wmlp reducer: 16384 elems/block ----
    const int base = bid * 16384;
    for (int i = tid; i < 16384; i += 512) {
      const int idx = base + i;
      const float s = wpart[idx] + wpart[65536 + idx]
                    + wpart[131072 + idx] + wpart[196608 + idx];
      wmlp[idx] = f2h(s);
    }
    return;
  }

  const int m0 = (RED ? (bid - 4) : bid) * 16;
  const int wid = tid >> 6, lane = tid & 63;
  const int lm = lane & 15, quad = lane >> 4;
  const float probe = bf2f(((const u16*)probew)[lane]);
  const bool f32 = __ballot(!(fabsf(probe) < 1000.0f)) != 0ull;

  floatx4 zero = {0.f, 0.f, 0.f, 0.f};
  floatx4 acc0 = zero, acc1 = zero;

  auto comb8 = [&](int t, int col8) -> short8 {
    const size_t o = (size_t)t * 256 + col8;
    const int h = col8 >> 5;
    const float m0_ = muc[t * 8 + h],          m1_ = muc[32768 + t * 8 + h];
    const float m2_ = muc[65536 + t * 8 + h],  m3_ = muc[98304 + t * 8 + h];
    const float M = fmaxf(fmaxf(m0_, m1_), fmaxf(m2_, m3_));
    float w0 = EX2(m0_ - M), w1 = EX2(m1_ - M), w2 = EX2(m2_ - M), w3 = EX2(m3_ - M);
    const float inv = 1.f / (w0 + w1 + w2 + w3);
    w0 *= inv; w1 *= inv; w2 *= inv; w3 *= inv;
    short8 a0 = *(const short8*)&A[o],  a1 = *(const short8*)&A[o + 1048576];
    short8 a2 = *(const short8*)&A2[o], a3 = *(const short8*)&A2[o + 1048576];
    float v[8];
#pragma unroll
    for (int j = 0; j < 8; ++j)
      v[j] = w0 * h2f((u16)a0[j]) + w1 * h2f((u16)a1[j])
           + w2 * h2f((u16)a2[j]) + w3 * h2f((u16)a3[j]);
    uint2v uu0 = {pkh2(v[0], v[1]), pkh2(v[2], v[3])};
    uint2v uu1 = {pkh2(v[4], v[5]), pkh2(v[6], v[7])};
    short8 r;
    *(uint2v*)&r = uu0; *((uint2v*)&r + 1) = uu1;
    return r;
  };

  const int arow = lane >> 2, aoff = (lane & 3) * 8;
  int brow0 = wid * 32 + (lane >> 2), brow1 = brow0 + 16;
  const int boff = (lane & 3) * 8;

  short8 ra, rb0, rb1;
  if (wid == 0) ra = comb8(m0 + arow, aoff);
  rb0 = *(const short8*)&Bt[(size_t)brow0 * 256 + boff];
  rb1 = *(const short8*)&Bt[(size_t)brow1 * 256 + boff];

  for (int k0 = 0; k0 < 256; k0 += 32) {
    if (k0) __syncthreads();
    if (wid == 0) *(short8*)&As[arow][aoff] = ra;
    *(short8*)&Bs[brow0][boff] = rb0;
    *(short8*)&Bs[brow1][boff] = rb1;
    __syncthreads();
    if (k0 + 32 < 256) {
      if (wid == 0) ra = comb8(m0 + arow, k0 + 32 + aoff);
      rb0 = *(const short8*)&Bt[(size_t)brow0 * 256 + k0 + 32 + boff];
      rb1 = *(const short8*)&Bt[(size_t)brow1 * 256 + k0 + 32 + boff];
    }
    half8 fa = *(const half8*)&As[lm][quad * 8];
    half8 fb0 = *(const half8*)&Bs[wid * 32 + lm][quad * 8];
    half8 fb1 = *(const half8*)&Bs[wid * 32 + 16 + lm][quad * 8];
    acc0 = MFMAG(fa, fb0, acc0);
    acc1 = MFMAG(fa, fb1, acc1);
  }

  const int col0 = wid * 32 + lm, col1 = col0 + 16;
  const float bv0 = h2f(bias[col0]), bv1 = h2f(bias[col1]);
  float s[4], sq[4], v0[4], v1[4];
#pragma unroll
  for (int r = 0; r < 4; ++r) {
    const int row = quad * 4 + r;
    const size_t o0 = (size_t)(m0 + row) * 256 + col0;
    const size_t o1 = (size_t)(m0 + row) * 256 + col1;
    const float x0 = f32 ? ((const float*)xraw)[o0] : bf2f(((const u16*)xraw)[o0]);
    const float x1 = f32 ? ((const float*)xraw)[o1] : bf2f(((const u16*)xraw)[o1]);
    const float a = acc0[r] + bv0 + h2f(f2h(x0));   // keep x->fp16->fp32 value path
    const float b = acc1[r] + bv1 + h2f(f2h(x1));
    v0[r] = a; v1[r] = b;
    s[r] = a + b; sq[r] = a * a + b * b;
  }
#pragma unroll
  for (int d = 1; d < 16; d <<= 1)
#pragma unroll
    for (int r = 0; r < 4; ++r) {
      s[r] += __shfl_xor(s[r], d);
      sq[r] += __shfl_xor(sq[r], d);
    }
  if (lm == 0)
#pragma unroll
    for (int r = 0; r < 4; ++r) { ss[wid][quad * 4 + r] = s[r]; ssq[wid][quad * 4 + r] = sq[r]; }
  __syncthreads();
#pragma unroll
  for (int r = 0; r < 4; ++r) {
    const int row = quad * 4 + r;
    float ts = 0.f, tq = 0.f;
#pragma unroll
    for (int w = 0; w < 8; ++w) { ts += ss[w][row]; tq += ssq[w][row]; }
    const float mean = ts * (1.f / 256.f);
    const float var = tq * (1.f / 256.f) - mean * mean;
    const float is = rsqrtf(var + 1e-5f);
    net[(size_t)(m0 + row) * 256 + col0] =
        f2h((v0[r] - mean) * is * h2f(g[col0]) + h2f(bb[col0]));
    net[(size_t)(m0 + row) * 256 + col1] =
        f2h((v1[r] - mean) * is * h2f(g[col1]) + h2f(bb[col1]));
  }
}

// ---------------- flash attention (+ optional split-K Wmlp at bids 0..63) ----
// WMLP=true: bid<64 computes one j-chunk (jc=bid&3, 256 js) of Wmlp tile
// (tile=bid>>2) -> fp32 partial wpart[jc][n][k]. attn at abid = bid - 64.
template<int CHUNKS, bool WMLP>
__global__ __launch_bounds__(256) void attn_k(
    const u16* __restrict__ qf16, const u16* __restrict__ kf16,
    const u16* __restrict__ vt, u16* __restrict__ outp, u16* __restrict__ out23,
    float* __restrict__ mu,
    const void* __restrict__ fc1_w, const void* __restrict__ fc2_w,
    float* __restrict__ wpart)
{
  __shared__ __align__(16) u16 Ks[2][64][32];    // [buf][key][d] fp16 (8KB)
  __shared__ __align__(16) u16 Vs[2][32][64];    // [buf][d][key] fp16 (8KB)
  const int tid = threadIdx.x, wid = tid >> 6, lane = tid & 63;
  const int lm = lane & 15, quad = lane >> 4;
  const int bid = blockIdx.x;

  if (WMLP && bid < 64) {        // ---- Wmlp split-K chunk (16 phases) ----
    const float probe = bf2f(((const u16*)fc2_w)[lane]);
    const bool f32 = __ballot(!(fabsf(probe) < 1000.0f)) != 0ull;
    #define RDW(p, i) (f32 ? ((const float*)(p))[i] : bf2f(((const u16*)(p))[i]))
    u16 (*As)[40] = (u16(*)[40])&Ks[0][0][0];
    u16 (*Bs)[40] = (u16(*)[40])&Vs[0][0][0];
    const int tile = bid >> 2, jc = bid & 3;
    const int tn = tile >> 2, tk2 = tile & 3;
    const int n0v = tn * 64, k0v = tk2 * 64;
    const int jbase = jc * 256;
    const int wm = (wid >> 1) * 32, wn = (wid & 1) * 32;
    floatx4 zero = {0.f, 0.f, 0.f, 0.f};
    floatx4 acc[2][2] = {{zero, zero}, {zero, zero}};
    const int an = tid & 63, aj8 = (tid >> 6) * 8;
    const int bk = tid >> 2, bj8 = (tid & 3) * 8;
    short8 ra, rb;
    auto ld = [&](int j0) {
      const int jg = jbase + j0;
#pragma unroll
      for (int jj = 0; jj < 8; ++jj)
        ra[jj] = (short)f2h(RDW(fc2_w, (size_t)(jg + aj8 + jj) * 256 + n0v + an));
      if (f32) {
        const float* bp = (const float*)fc1_w + (size_t)(k0v + bk) * 1024 + jg + bj8;
        floatx4 b0 = *(const floatx4*)bp;
        floatx4 b1 = *(const floatx4*)(bp + 4);
#pragma unroll
        for (int jj = 0; jj < 4; ++jj) {
          rb[jj]     = (short)f2h(b0[jj]);
          rb[4 + jj] = (short)f2h(b1[jj]);
        }
      } else {
        short8 bbv = *(const short8*)((const u16*)fc1_w +
                                      (size_t)(k0v + bk) * 1024 + jg + bj8);
#pragma unroll
        for (int jj = 0; jj < 8; ++jj) rb[jj] = (short)f2h(bf2f((u16)bbv[jj]));
      }
    };
    ld(0);
    for (int j0 = 0; j0 < 256; j0 += 32) {
      if (j0) __syncthreads();
      *(short8*)&As[an][aj8] = ra;
      *(short8*)&Bs[bk][bj8] = rb;
      __syncthreads();
      if (j0 + 32 < 256) ld(j0 + 32);
      half8 fa[2], fb[2];
#pragma unroll
      for (int t = 0; t < 2; ++t) {
        fa[t] = *(const half8*)&As[wm + t * 16 + lm][quad * 8];
        fb[t] = *(const half8*)&Bs[wn + t * 16 + lm][quad * 8];
      }
#pragma unroll
      for (int i = 0; i < 2; ++i)
#pragma unroll
        for (int j = 0; j < 2; ++j)
          acc[i][j] = MFMAG(fa[i], fb[j], acc[i][j]);
    }
    float* wp = wpart + (size_t)jc * 65536;
#pragma unroll
    for (int i = 0; i < 2; ++i) {
      const int rown = n0v + wm + i * 16 + quad * 4;
#pragma unroll
      for (int j = 0; j < 2; ++j) {
        const int colk = k0v + wn + j * 16 + lm;
#pragma unroll
        for (int r = 0; r < 4; ++r)
          wp[(size_t)(rown + r) * 256 + colk] = acc[i][j][r];
      }
    }
    #undef RDW
    return;
  }

  const int abid = WMLP ? bid - 64 : bid;
  const int chunk = (CHUNKS > 1) ? (abid >> 9) : 0;
  const int qblk = abid & 31, bh = (abid >> 5) & 15;
  const int b = bh >> 3, h = bh & 7;
  const int q0 = qblk * 64 + wid * 16;
  const size_t tb = (size_t)b * 2048;
  const int NT = 32 / CHUNKS;
  const int kofs = chunk * (2048 / CHUNKS);

  half8 qh;
  { size_t off = (tb + q0 + lm) * 256 + h * 32 + quad * 8;
    qh = *(const half8*)&qf16[off]; }

  const int kkey = tid >> 2, kg = tid & 3;
  const size_t kb = (tb + kofs + kkey) * 256 + h * 32 + kg * 8;
  const int vd = tid >> 3, vp = tid & 7, vk8 = vp ^ (vd & 7);
  const size_t vb = (size_t)(bh * 32 + vd) * 2048 + kofs + vk8 * 8;

  gll16(kf16 + kb, (u16*)Ks + tid * 8);
  gll16(vt  + vb,  (u16*)Vs + tid * 8);

  float mrun = -1e30f, lrun = 0.f;
  floatx4 o0 = {0.f,0.f,0.f,0.f}, o1 = {0.f,0.f,0.f,0.f};

  for (int kt = 0; kt < NT; ++kt) {
    const int buf = kt & 1;
    __syncthreads();
    if (kt < NT - 1) {
      const int nb = (buf ^ 1) * 2048;
      const size_t ko = (size_t)(kt + 1) * 16384;
      const size_t vo = (size_t)(kt + 1) * 64;
      gll16(kf16 + kb + ko, (u16*)Ks + nb + tid * 8);
      gll16(vt  + vb + vo,  (u16*)Vs + nb + tid * 8);
    }

    floatx4 z[4];
#pragma unroll
    for (int kf = 0; kf < 4; ++kf) {
      half8 khf = *(const half8*)&Ks[buf][kf * 16 + lm][quad * 8];
      floatx4 zz = {0.f,0.f,0.f,0.f};
      z[kf] = MFMAG(khf, qh, zz);
    }
    float zm = fmaxf(fmaxf(fmaxf(z[0][0], z[0][1]), fmaxf(z[0][2], z[0][3])),
               fmaxf(fmaxf(z[1][0], z[1][1]), fmaxf(z[1][2], z[1][3])));
    zm = fmaxf(zm, fmaxf(fmaxf(fmaxf(z[2][0], z[2][1]), fmaxf(z[2][2], z[2][3])),
                   fmaxf(fmaxf(z[3][0], z[3][1]), fmaxf(z[3][2], z[3][3]))));
    zm = fmaxf(zm, __shfl_xor(zm, 16));
    zm = fmaxf(zm, __shfl_xor(zm, 32));
    const float mn = fmaxf(mrun, zm);
    const float alpha = EX2((mrun - mn) * CLF);
    const float mc = mn * CLF;
    mrun = mn;
    float ls = 0.f;
    half4 pb[4];
#pragma unroll
    for (int kf = 0; kf < 4; ++kf) {
      const float p0 = EX2(__builtin_fmaf(z[kf][0], CLF, -mc));
      const float p1 = EX2(__builtin_fmaf(z[kf][1], CLF, -mc));
      const float p2 = EX2(__builtin_fmaf(z[kf][2], CLF, -mc));
      const float p3 = EX2(__builtin_fmaf(z[kf][3], CLF, -mc));
      ls += (p0 + p1) + (p2 + p3);
      uint2v uu = {pkh2(p0, p1), pkh2(p2, p3)};
      pb[kf] = *(half4*)&uu;
    }
    ls += __shfl_xor(ls, 16);
    ls += __shfl_xor(ls, 32);
    lrun = lrun * alpha + ls;
#pragma unroll
    for (int r = 0; r < 4; ++r) { o0[r] *= alpha; o1[r] *= alpha; }
    const u16* vbase = (const u16*)Vs + buf * 2048;
#pragma unroll
    for (int kf = 0; kf < 4; ++kf) {
      const int k8 = 2 * kf + (quad >> 1);
      const int d0 = lm, d1 = 16 + lm;
      half4 vf0 = *(const half4*)(vbase + (d0 * 8 + (k8 ^ (d0 & 7))) * 8 + (quad & 1) * 4);
      half4 vf1 = *(const half4*)(vbase + (d1 * 8 + (k8 ^ (d1 & 7))) * 8 + (quad & 1) * 4);
      o0 = MFMAPV(vf0, pb[kf], o0);
      o1 = MFMAPV(vf1, pb[kf], o1);
    }
  }
  const float inv = 1.0f / lrun;
  const size_t tok = tb + q0 + lm;
  u16* dst = ((CHUNKS > 2 && chunk >= 2) ? out23 : outp) + (size_t)(chunk & 1) * 1048576;
  const size_t rowo = tok * 256 + h * 32;
#pragma unroll
  for (int r = 0; r < 4; ++r) {
    dst[rowo + quad * 4 + r]      = f2h(o0[r] * inv);
    dst[rowo + 16 + quad * 4 + r] = f2h(o1[r] * inv);
  }
  if (CHUNKS > 1 && quad == 0)
    mu[chunk * 32768 + tok * 8 + h] = __builtin_fmaf(mrun, CLF, __log2f(lrun));
}

// ---------------- combine (fallback, sk2 path only) ----------------
template<int CHUNKS>
__global__ __launch_bounds__(256) void combine_k(u16* __restrict__ d,
                                                 const u16* __restrict__ e,
                                                 const float* __restrict__ mu)
{
  const int t = blockIdx.x, c = threadIdx.x, h = c >> 5;
  const size_t o = (size_t)t * 256 + c;
  float m[CHUNKS];
  float M = -1e30f;
#pragma unroll
  for (int i = 0; i < CHUNKS; ++i) { m[i] = mu[i * 32768 + t * 8 + h]; M = fmaxf(M, m[i]); }
  float wsum = 0.f, acc = 0.f;
#pragma unroll
  for (int i = 0; i < CHUNKS; ++i) {
    const float w = EX2(m[i] - M);
    const u16 v = (i < 2) ? d[o + (size_t)i * 1048576] : e[o + (size_t)(i - 2) * 1048576];
    wsum += w; acc += w * h2f(v);
  }
  d[o] = f2h(acc / wsum);
}

// ---------------- residual add + LayerNorm (fallback paths only) ----------------
__global__ __launch_bounds__(256) void ln_k(const float* __restrict__ pf,
                                            const u16* __restrict__ xh,
                                            const u16* __restrict__ g,
                                            const u16* __restrict__ bta,
                                            u16* __restrict__ net)
{
  const int t = blockIdx.x, c = threadIdx.x;
  const size_t o = (size_t)t * 256 + c;
  float v = pf[o] + h2f(xh[o]);
  float s = v, s2 = v * v;
#pragma unroll
  for (int d = 1; d < 64; d <<= 1) { s += __shfl_xor(s, d); s2 += __shfl_xor(s2, d); }
  __shared__ float ss[4], ss2[4];
  const int w = c >> 6;
  if ((c & 63) == 0) { ss[w] = s; ss2[w] = s2; }
  __syncthreads();
  s = ss[0] + ss[1] + ss[2] + ss[3];
  s2 = ss2[0] + ss2[1] + ss2[2] + ss2[3];
  const float mu = s * (1.f / 256.f);
  const float var = s2 * (1.f / 256.f) - mu * mu;
  const float is = rsqrtf(var + 1e-5f);
  net[o] = f2h((v - mu) * is * h2f(g[c]) + h2f(bta[c]));
}

extern "C" void kernel_launch(void* const* d_in, const int* in_sizes, int n_in,
                              void* d_out, int out_size, void* d_ws, size_t ws_size,
                              hipStream_t stream) {
  const void* x      = d_in[0];
  const void* qkv_w  = d_in[1];
  const void* proj_w = d_in[2];
  const void* proj_b = d_in[3];
  const void* fc1_w  = d_in[4];
  const void* fc1_b  = d_in[5];
  const void* fc2_w  = d_in[6];
  const void* fc2_b  = d_in[7];
  const void* ln_g   = d_in[8];
  const void* ln_b   = d_in[9];

  char* ws = (char*)d_ws;
  u16* b_proj  = (u16*)(ws + 4096);
  u16* b_fc1   = (u16*)(ws + 8192);
  u16* bmlp    = (u16*)(ws + 12288);     // sk4: bmlp; fallback: b_fc2
  u16* b_fc2   = (u16*)(ws + 12288);
  u16* g_ln    = (u16*)(ws + 16384);
  u16* bb_ln   = (u16*)(ws + 20480);
  u16* wq_f    = (u16*)(ws + 131072);    // fallback only
  u16* wt_proj = (u16*)(ws + 524288);
  u16* wt_fc1  = (u16*)(ws + 655360);    // fallback only
  u16* wt_fc2  = (u16*)(ws + 1179648);   // fallback only
  u16* wmlp    = (u16*)(ws + 1703936);   // sk4: [256 n][256 k] fp16, 128KB
  u16* x_f     = (u16*)(ws + 2097152);   // fallback only
  u16* q_f16   = (u16*)(ws + 4194304);
  u16* k_f16   = (u16*)(ws + 6291456);
  u16* vt      = (u16*)(ws + 8388608);
  float* mu    = (float*)(ws + 10485760);
  u16* out23   = (u16*)(ws + 11010048);  // -> 15204352
  float* wpart = (float*)(ws + 15204352);// [4][256][256] fp32, 1MB -> 16252928
  u16* attn    = (u16*)d_out;            // chunks 0,1 (d_out scratch until mlp)

  // sk4 path: net over the (unused) x_f region
  u16* net4    = (u16*)(ws + 2097152);

  // fallback-path buffers
  float* projf = (float*)(ws + 4194304);
  u16* net     = (u16*)(ws + 11010048);
  u16* hbuf    = (u16*)(ws + 2097152);

  const bool sk4 = ws_size >= 16252928;    // call-invariant -> graph-safe
  const bool sk2 = ws_size >= 11010048;

  if (sk4) {
    // 1) qkv GEMM from raw inputs + proj transpose + bmlp + params
    qkvprep_k<<<789, 256, 0, stream>>>(x, qkv_w, proj_w, proj_b,
                                       fc1_b, fc2_w, fc2_b, ln_g, ln_b,
                                       wt_proj, bmlp, b_proj, g_ln, bb_ln,
                                       vt, q_f16, k_f16);
    // 2) attention (4-way split-K) + 64 split-K Wmlp chunks at bids 0..63
    attn_k<4, true><<<2112, 256, 0, stream>>>(q_f16, k_f16, vt, attn, out23, mu,
                                              fc1_w, fc2_w, wpart);
    // 3) proj+combine+bias+residual+LN (bids 4..259) + wmlp reduce (bids 0..3)
    projln8_k<true><<<260, 512, 0, stream>>>(attn, out23, wt_proj, b_proj, x, qkv_w,
                                             g_ln, bb_ln, mu, net4, wpart, wmlp);
    // 4) collapsed MLP: out = net @ Wmlp + bmlp + net -> d_out fp32
    gemm_k<2, 0, true, true, false><<<dim3(4, 64), 256, 0, stream>>>(
        net4, wmlp, nullptr, bmlp, net4, d_out, nullptr, nullptr, nullptr,
        4096, 256, 256);
    return;
  }

  prep_k<<<1224, 256, 0, stream>>>(x, qkv_w, proj_w, fc1_w, fc2_w,
                                   proj_b, fc1_b, fc2_b, ln_g, ln_b,
                                   x_f, wq_f, wt_proj, wt_fc1, wt_fc2,
                                   b_proj, b_fc1, b_fc2, g_ln, bb_ln);
  gemm_k<2, 2, false, false, false><<<dim3(12, 64), 256, 0, stream>>>(
      x_f, wq_f, nullptr, nullptr, nullptr, vt, q_f16, k_f16, nullptr, 4096, 768, 256);
  if (sk2) {
    attn_k<2, false><<<1024, 256, 0, stream>>>(q_f16, k_f16, vt, attn, nullptr, mu,
                                               nullptr, nullptr, nullptr);
    combine_k<2><<<4096, 256, 0, stream>>>(attn, nullptr, mu);
    gemm_k<2, 0, true, false, false><<<dim3(4, 64), 256, 0, stream>>>(
        attn, wt_proj, nullptr, b_proj, nullptr, projf, nullptr, nullptr, nullptr,
        4096, 256, 256);
  } else {
    attn_k<1, false><<<512, 256, 0, stream>>>(q_f16, k_f16, vt, attn, nullptr, nullptr,
                                              nullptr, nullptr, nullptr);
    gemm_k<2, 0, true, false, false><<<dim3(4, 64), 256, 0, stream>>>(
        attn, wt_proj, nullptr, b_proj, nullptr, projf, nullptr, nullptr, nullptr,
        4096, 256, 256);
  }
  ln_k<<<4096, 256, 0, stream>>>(projf, x_f, g_ln, bb_ln, net);
  gemm_k<2, 1, true, false, false><<<dim3(16, 64), 256, 0, stream>>>(
      net, wt_fc1, nullptr, b_fc1, nullptr, hbuf, nullptr, nullptr, nullptr,
      4096, 1024, 256);
  gemm_k<2, 0, true, true, false><<<dim3(4, 64), 256, 0, stream>>>(
      hbuf, wt_fc2, nullptr, b_fc2, net, d_out, nullptr, nullptr, nullptr,
      4096, 256, 1024);
}

// Round 14
// 140.533 us; speedup vs baseline: 1.0630x; 1.0380x over previous
//
#include <hip/hip_runtime.h>

// B=2,N=2048,D=256,H=8,HD=32,DFF=1024. SCALE MULTIPLIES by sqrt(32). No MLP
// activation. Post-norm. Inputs fp32 (auto-detected), output fp32.
// R29 = REVERT to R24 (141.2us, best verified). The MLP-collapse family
// (R25-R28: 169.6/144.7/149.4/145.9) is abandoned: the Wmlp pole (~13-16us of
// extra serial work) cannot hide in a pipeline whose dispatches are 15-40us.
// Structure: qkvprep (qkv GEMM from raw inputs + weight transposes + biases,
// 920 blocks) -> attn<4> -> projln8 (proj+combine+bias+residual+LN) -> fc1 ->
// fc2 (8-wave). 5 dispatches.

typedef __attribute__((ext_vector_type(8))) short short8;       // raw 16B
typedef __attribute__((ext_vector_type(4))) short short4v;      // raw 8B
typedef __attribute__((ext_vector_type(8))) _Float16 half8;     // 8 fp16 = 4 VGPRs
typedef __attribute__((ext_vector_type(4))) _Float16 half4;     // 4 fp16 = 2 VGPRs
typedef __attribute__((ext_vector_type(2))) __fp16 fp16x2;      // cvt_pkrtz return type
typedef __attribute__((ext_vector_type(4))) float floatx4;
typedef __attribute__((ext_vector_type(2))) unsigned int uint2v;
typedef unsigned short u16;

#define MFMAG(a,b,c)  __builtin_amdgcn_mfma_f32_16x16x32_f16((a),(b),(c),0,0,0)
#if __has_builtin(__builtin_amdgcn_mfma_f32_16x16x16_f16)
#define MFMAPV(a,b,c) __builtin_amdgcn_mfma_f32_16x16x16_f16((a),(b),(c),0,0,0)
#else
#define MFMAPV(a,b,c) __builtin_amdgcn_mfma_f32_16x16x16f16((a),(b),(c),0,0,0)
#endif
#define CLF 8.1615404f   // SCALE * log2(e)

#if __has_builtin(__builtin_amdgcn_exp2f)
#define EX2(x) __builtin_amdgcn_exp2f(x)
#else
#define EX2(x) exp2f(x)
#endif

__device__ __forceinline__ float bf2f(u16 u) { return __uint_as_float(((unsigned)u) << 16); }
__device__ __forceinline__ float h2f(u16 u) { _Float16 h = *(_Float16*)&u; return (float)h; }
__device__ __forceinline__ u16 f2h(float f) { _Float16 h = (_Float16)f; return *(u16*)&h; }
// pack 2 fp32 -> 2 fp16 (RTZ), 1 VALU
__device__ __forceinline__ unsigned pkh2(float a, float b) {
#if __has_builtin(__builtin_amdgcn_cvt_pkrtz)
  fp16x2 h = __builtin_amdgcn_cvt_pkrtz(a, b);
  return *(unsigned*)&h;
#else
  return (unsigned)f2h(a) | ((unsigned)f2h(b) << 16);
#endif
}
// async global->LDS, 16B/lane; LDS dest = wave-uniform base + lane*16 (m104)
__device__ __forceinline__ void gll16(const void* g, void* l) {
  __builtin_amdgcn_global_load_lds((const __attribute__((address_space(1))) void*)g,
                                   (__attribute__((address_space(3))) void*)l, 16, 0, 0);
}

// ---------------- fused qkv GEMM (reads raw fp32/bf16 inputs) + prep-rest ------------
// Grid 920 x 256 thr. bid<768: qkv 64x64 tile (mb=bid/12, nb=bid%12), A=x raw,
// B=qkv_w raw transposed-in-staging; EPI2 epilogue (Q->qf, K->kf, V->vt).
// bid>=768: 144 transpose tiles (proj/fc1/fc2) + 8 bias blocks.
__global__ __launch_bounds__(256) void qkvprep_k(
    const void* __restrict__ x, const void* __restrict__ qkv_w,
    const void* __restrict__ proj_w, const void* __restrict__ fc1_w,
    const void* __restrict__ fc2_w, const void* __restrict__ proj_b,
    const void* __restrict__ fc1_b, const void* __restrict__ fc2_b,
    const void* __restrict__ ln_g, const void* __restrict__ ln_b,
    u16* __restrict__ wt_proj, u16* __restrict__ wt_fc1, u16* __restrict__ wt_fc2,
    u16* __restrict__ b_proj, u16* __restrict__ b_fc1, u16* __restrict__ b_fc2,
    u16* __restrict__ g_ln, u16* __restrict__ bb_ln,
    u16* __restrict__ vt, u16* __restrict__ qf, u16* __restrict__ kf)
{
  __shared__ __align__(16) u16 lds[9728];   // As(2560)|Bs(2560)|Vt(4608); tr aliases
  const int tid = threadIdx.x;
  const int lane = tid & 63;
  const float probe = bf2f(((const u16*)qkv_w)[lane]);
  const bool f32 = __ballot(!(fabsf(probe) < 1000.0f)) != 0ull;
  const int bid = blockIdx.x;
  #define RD(p, i) (f32 ? ((const float*)(p))[i] : bf2f(((const u16*)(p))[i]))

  if (bid >= 768) {               // ---- prep-rest: weight transposes + biases ----
    int idx = bid - 768;
    if (idx < 144) {
      u16 (*tr)[70] = (u16(*)[70])lds;
      const void* src; u16* dst; int Ns, Kt, tk, tn;
      if (idx < 16)      { src = proj_w; dst = wt_proj; Ns = 256;  Kt = 256;
                           tk = idx & 3;  tn = idx >> 2; }
      else if (idx < 80) { idx -= 16; src = fc1_w; dst = wt_fc1; Ns = 1024; Kt = 256;
                           tk = idx & 3;  tn = idx >> 2; }
      else               { idx -= 80; src = fc2_w; dst = wt_fc2; Ns = 256;  Kt = 1024;
                           tk = idx & 15; tn = idx >> 4; }
      const int k0 = tk * 64, n0v = tn * 64;
      const int r = tid >> 6, c = tid & 63;
#pragma unroll
      for (int p = 0; p < 16; ++p) {
        const int k = k0 + p * 4 + r;
        tr[c][p * 4 + r] = f2h(RD(src, (size_t)k * Ns + n0v + c));
      }
      __syncthreads();
#pragma unroll
      for (int p = 0; p < 16; ++p) {
        const int n = n0v + p * 4 + r;
        dst[(size_t)n * Kt + k0 + c] = tr[p * 4 + r][c];
      }
    } else {
      const int j = (idx - 144) * 256 + tid;
      if (j < 256)       b_proj[j]        = f2h(RD(proj_b, j));
      else if (j < 1280) b_fc1[j - 256]   = f2h(RD(fc1_b, j - 256));
      else if (j < 1536) b_fc2[j - 1280]  = f2h(RD(fc2_b, j - 1280));
      else if (j < 1792) g_ln[j - 1536]   = f2h(RD(ln_g, j - 1536));
      else if (j < 2048) bb_ln[j - 1792]  = f2h(RD(ln_b, j - 1792));
    }
    return;
  }

  // ---- qkv GEMM path ----
  u16 (*As)[40] = (u16(*)[40])lds;
  u16 (*Bs)[40] = (u16(*)[40])(lds + 2560);
  u16* Vt = lds + 5120;
  const int mb = bid / 12, nb = bid % 12;
  const int m0 = mb * 64, n0 = nb * 64;
  const int wid = tid >> 6;
  const int wm = (wid >> 1) * 32, wn = (wid & 1) * 32;
  const int lm = lane & 15, quad = lane >> 4;

  floatx4 zero = {0.f, 0.f, 0.f, 0.f};
  floatx4 acc[2][2] = {{zero, zero}, {zero, zero}};

  // staging assignment: A: 4 thr/row x 8 k; B: thread owns col bn, k-octet bk8
  const int arow = tid >> 2, aoff = (tid & 3) * 8;
  const int bn = tid & 63, bk8 = (tid >> 6) * 8;

  short8 rah, rbh;
  auto ld = [&](int kk) {
    if (f32) {
      const float* xp = (const float*)x + (size_t)(m0 + arow) * 256 + kk + aoff;
      floatx4 a0 = *(const floatx4*)xp;
      floatx4 a1 = *(const floatx4*)(xp + 4);
#pragma unroll
      for (int j = 0; j < 4; ++j) {
        rah[j]     = (short)f2h(a0[j]);
        rah[4 + j] = (short)f2h(a1[j]);
      }
      const float* wp = (const float*)qkv_w + (size_t)(kk + bk8) * 768 + n0 + bn;
#pragma unroll
      for (int j = 0; j < 8; ++j) rbh[j] = (short)f2h(wp[(size_t)j * 768]);
    } else {
      short8 a = *(const short8*)((const u16*)x + (size_t)(m0 + arow) * 256 + kk + aoff);
#pragma unroll
      for (int j = 0; j < 8; ++j) rah[j] = (short)f2h(bf2f((u16)a[j]));
      const u16* wp = (const u16*)qkv_w + (size_t)(kk + bk8) * 768 + n0 + bn;
#pragma unroll
      for (int j = 0; j < 8; ++j) rbh[j] = (short)f2h(bf2f(wp[(size_t)j * 768]));
    }
  };
  ld(0);
  for (int k0 = 0; k0 < 256; k0 += 32) {
    if (k0) __syncthreads();
    *(short8*)&As[arow][aoff] = rah;
    *(short8*)&Bs[bn][bk8] = rbh;
    __syncthreads();
    if (k0 + 32 < 256) ld(k0 + 32);     // next-tile loads fly during MFMAs
    half8 fa[2], fb[2];
#pragma unroll
    for (int t = 0; t < 2; ++t) {
      fa[t] = *(const half8*)&As[wm + t * 16 + lm][quad * 8];
      fb[t] = *(const half8*)&Bs[wn + t * 16 + lm][quad * 8];
    }
#pragma unroll
    for (int i = 0; i < 2; ++i)
#pragma unroll
      for (int j = 0; j < 2; ++j)
        acc[i][j] = MFMAG(fa[i], fb[j], acc[i][j]);
  }
  #undef RD

  // ---- V epilogue (n0>=512): C -> LDS transpose -> coalesced vt rows ----
  if (n0 >= 512) {
    __syncthreads();
#pragma unroll
    for (int i = 0; i < 2; ++i)
#pragma unroll
      for (int j = 0; j < 2; ++j)
#pragma unroll
        for (int r = 0; r < 4; ++r)
          Vt[(wn + j * 16 + lm) * 72 + wm + i * 16 + quad * 4 + r] = f2h(acc[i][j][r]);
    __syncthreads();
    const int bb = m0 >> 11, n = m0 & 2047;
#pragma unroll
    for (int pass = 0; pass < 2; ++pass) {
      const int dl = (tid >> 3) + pass * 32;     // local col 0..63
      const int oct = tid & 7;                   // token octet
      const int col = n0 - 512 + dl;             // 0..255
      const int d = col & 31, hh = col >> 5;
      short8 v = *(const short8*)&Vt[dl * 72 + oct * 8];
      *(short8*)&vt[(size_t)((bb * 8 + hh) * 32 + d) * 2048 + n + oct * 8] = v;
    }
    return;
  }

  // ---- Q/K epilogue ----
#pragma unroll
  for (int i = 0; i < 2; ++i) {
    const int rowb = m0 + wm + i * 16 + quad * 4;
#pragma unroll
    for (int j = 0; j < 2; ++j) {
      const int col = n0 + wn + j * 16 + lm;
#pragma unroll
      for (int r = 0; r < 4; ++r) {
        const int row = rowb + r;
        const u16 hv = f2h(acc[i][j][r]);
        if (col < 256) qf[(size_t)row * 256 + col] = hv;
        else           kf[(size_t)row * 256 + (col - 256)] = hv;
      }
    }
  }
}

// ---------------- prep (FALLBACK paths only) ----------------
__global__ __launch_bounds__(256) void prep_k(
    const void* __restrict__ x, const void* __restrict__ qkv_w,
    const void* __restrict__ proj_w, const void* __restrict__ fc1_w,
    const void* __restrict__ fc2_w, const void* __restrict__ proj_b,
    const void* __restrict__ fc1_b, const void* __restrict__ fc2_b,
    const void* __restrict__ ln_g, const void* __restrict__ ln_b,
    u16* __restrict__ x_f, u16* __restrict__ wq_f,
    u16* __restrict__ wt_proj, u16* __restrict__ wt_fc1, u16* __restrict__ wt_fc2,
    u16* __restrict__ b_proj, u16* __restrict__ b_fc1, u16* __restrict__ b_fc2,
    u16* __restrict__ g_ln, u16* __restrict__ bb_ln)
{
  __shared__ u16 tr[64][70];
  const int lane = threadIdx.x & 63;
  const float probe = bf2f(((const u16*)qkv_w)[lane]);
  const bool f32 = __ballot(!(fabsf(probe) < 1000.0f)) != 0ull;
  const int bid = blockIdx.x, tid = threadIdx.x;
  #define RD(p, i) (f32 ? ((const float*)(p))[i] : bf2f(((const u16*)(p))[i]))
  if (bid < 1024) {
    const size_t i = (size_t)bid * 1024 + tid * 4;
    const u16 o0 = f2h(RD(x, i)),     o1 = f2h(RD(x, i + 1));
    const u16 o2 = f2h(RD(x, i + 2)), o3 = f2h(RD(x, i + 3));
    short4v sv = {(short)o0, (short)o1, (short)o2, (short)o3};
    *(short4v*)&x_f[i] = sv;
  } else if (bid < 1216) {
    int idx = bid - 1024;
    const void* src; u16* dst; int Ns, Kt, tk, tn;
    if (idx < 48)       { src = qkv_w;  dst = wq_f;    Ns = 768;  Kt = 256;
                          tk = idx & 3;  tn = idx >> 2; }
    else if (idx < 64)  { idx -= 48;  src = proj_w; dst = wt_proj; Ns = 256; Kt = 256;
                          tk = idx & 3;  tn = idx >> 2; }
    else if (idx < 128) { idx -= 64;  src = fc1_w;  dst = wt_fc1;  Ns = 1024; Kt = 256;
                          tk = idx & 3;  tn = idx >> 2; }
    else                { idx -= 128; src = fc2_w;  dst = wt_fc2;  Ns = 256;  Kt = 1024;
                          tk = idx & 15; tn = idx >> 4; }
    const int k0 = tk * 64, n0 = tn * 64;
    const int r = tid >> 6, c = tid & 63;
#pragma unroll
    for (int p = 0; p < 16; ++p) {
      const int k = k0 + p * 4 + r;
      tr[c][p * 4 + r] = f2h(RD(src, (size_t)k * Ns + n0 + c));
    }
    __syncthreads();
#pragma unroll
    for (int p = 0; p < 16; ++p) {
      const int n = n0 + p * 4 + r;
      dst[(size_t)n * Kt + k0 + c] = tr[p * 4 + r][c];
    }
  } else {
    const int j = (bid - 1216) * 256 + tid;
    if (j < 256)       b_proj[j]        = f2h(RD(proj_b, j));
    else if (j < 1280) b_fc1[j - 256]   = f2h(RD(fc1_b, j - 256));
    else if (j < 1536) b_fc2[j - 1280]  = f2h(RD(fc2_b, j - 1280));
    else if (j < 1792) g_ln[j - 1536]   = f2h(RD(ln_g, j - 1536));
    else if (j < 2048) bb_ln[j - 1792]  = f2h(RD(ln_b, j - 1792));
  }
  #undef RD
}

// ---------------- GEMM (fp16, fp32 accum) with register-prefetch staging ----------------
template<int TW, int EPI, bool BIAS, bool RES, bool COMB>
__global__ __launch_bounds__(256) void gemm_k(
    const u16* __restrict__ A, const u16* __restrict__ Bt, const u16* __restrict__ A2,
    const u16* __restrict__ bias, const u16* __restrict__ res,
    void* __restrict__ out0, u16* __restrict__ aux1, u16* __restrict__ aux3,
    const float* __restrict__ muc,
    int M, int Nn, int K)
{
  constexpr int BT = TW * 32;
  constexpr int NC = TW / 2;
  __shared__ __align__(16) u16 As[BT][40];
  __shared__ __align__(16) u16 Bs[BT][40];
  __shared__ __align__(16) u16 Vt[(EPI == 2) ? 64 * 72 : 1];
  const int tid = threadIdx.x;
  const int m0 = blockIdx.y * BT, n0 = blockIdx.x * BT;
  const int wid = tid >> 6, lane = tid & 63;
  const int wm = (wid >> 1) * (TW * 16), wn = (wid & 1) * (TW * 16);
  const int lm = lane & 15, quad = lane >> 4;

  floatx4 zero = {0.f, 0.f, 0.f, 0.f};
  floatx4 acc[TW][TW];
#pragma unroll
  for (int i = 0; i < TW; ++i)
#pragma unroll
    for (int j = 0; j < TW; ++j) acc[i][j] = zero;

  auto comb8 = [&](int t, int col8) -> short8 {
    const size_t o = (size_t)t * 256 + col8;
    const int h = col8 >> 5;
    const float m0_ = muc[t * 8 + h],          m1_ = muc[32768 + t * 8 + h];
    const float m2_ = muc[65536 + t * 8 + h],  m3_ = muc[98304 + t * 8 + h];
    const float M = fmaxf(fmaxf(m0_, m1_), fmaxf(m2_, m3_));
    float w0 = EX2(m0_ - M), w1 = EX2(m1_ - M), w2 = EX2(m2_ - M), w3 = EX2(m3_ - M);
    const float inv = 1.f / (w0 + w1 + w2 + w3);
    w0 *= inv; w1 *= inv; w2 *= inv; w3 *= inv;
    short8 a0 = *(const short8*)&A[o],  a1 = *(const short8*)&A[o + 1048576];
    short8 a2 = *(const short8*)&A2[o], a3 = *(const short8*)&A2[o + 1048576];
    float v[8];
#pragma unroll
    for (int j = 0; j < 8; ++j)
      v[j] = w0 * h2f((u16)a0[j]) + w1 * h2f((u16)a1[j])
           + w2 * h2f((u16)a2[j]) + w3 * h2f((u16)a3[j]);
    uint2v uu0 = {pkh2(v[0], v[1]), pkh2(v[2], v[3])};
    uint2v uu1 = {pkh2(v[4], v[5]), pkh2(v[6], v[7])};
    short8 r;
    *(uint2v*)&r = uu0; *((uint2v*)&r + 1) = uu1;
    return r;
  };

  int srow[NC], soff[NC];
#pragma unroll
  for (int c = 0; c < NC; ++c) {
    const int cid = tid * NC + c;
    srow[c] = cid >> 2; soff[c] = (cid & 3) * 8;
  }

  short8 ra0[NC], rb0[NC];
  auto ld = [&](int kk) {
#pragma unroll
    for (int c = 0; c < NC; ++c) {
      rb0[c] = *(const short8*)&Bt[(size_t)(n0 + srow[c]) * K + kk + soff[c]];
      if (COMB) ra0[c] = comb8(m0 + srow[c], kk + soff[c]);
      else      ra0[c] = *(const short8*)&A[(size_t)(m0 + srow[c]) * K + kk + soff[c]];
    }
  };
  ld(0);
  for (int k0 = 0; k0 < K; k0 += 32) {
    if (k0) __syncthreads();
#pragma unroll
    for (int c = 0; c < NC; ++c) {
      *(short8*)&As[srow[c]][soff[c]] = ra0[c];
      *(short8*)&Bs[srow[c]][soff[c]] = rb0[c];
    }
    __syncthreads();
    if (k0 + 32 < K) ld(k0 + 32);
    half8 fa[TW], fb[TW];
#pragma unroll
    for (int t = 0; t < TW; ++t) {
      fa[t] = *(const half8*)&As[wm + t * 16 + lm][quad * 8];
      fb[t] = *(const half8*)&Bs[wn + t * 16 + lm][quad * 8];
    }
#pragma unroll
    for (int i = 0; i < TW; ++i)
#pragma unroll
      for (int j = 0; j < TW; ++j)
        acc[i][j] = MFMAG(fa[i], fb[j], acc[i][j]);
  }

  if (EPI == 2 && n0 >= 512) {
    __syncthreads();
#pragma unroll
    for (int i = 0; i < TW; ++i)
#pragma unroll
      for (int j = 0; j < TW; ++j)
#pragma unroll
        for (int r = 0; r < 4; ++r)
          Vt[(wn + j * 16 + lm) * 72 + wm + i * 16 + quad * 4 + r] = f2h(acc[i][j][r]);
    __syncthreads();
    const int bb = m0 >> 11, n = m0 & 2047;
#pragma unroll
    for (int pass = 0; pass < 2; ++pass) {
      const int dl = (tid >> 3) + pass * 32;
      const int oct = tid & 7;
      const int col = n0 - 512 + dl;
      const int d = col & 31, hh = col >> 5;
      short8 v = *(const short8*)&Vt[dl * 72 + oct * 8];
      *(short8*)&((u16*)out0)[(size_t)((bb * 8 + hh) * 32 + d) * 2048 + n + oct * 8] = v;
    }
    return;
  }

#pragma unroll
  for (int i = 0; i < TW; ++i) {
    const int rowb = m0 + wm + i * 16 + quad * 4;
#pragma unroll
    for (int j = 0; j < TW; ++j) {
      const int col = n0 + wn + j * 16 + lm;
      const float bv = BIAS ? h2f(bias[col]) : 0.f;
#pragma unroll
      for (int r = 0; r < 4; ++r) {
        const int row = rowb + r;
        float v = acc[i][j][r] + bv;
        const size_t o = (size_t)row * Nn + col;
        if (RES) v += h2f(res[o]);
        if (EPI == 0) {
          ((float*)out0)[o] = v;
        } else if (EPI == 1) {
          ((u16*)out0)[o] = f2h(v);
        } else {
          if (col < 256) aux1[(size_t)row * 256 + col] = f2h(v);
          else           aux3[(size_t)row * 256 + (col - 256)] = f2h(v);
        }
      }
    }
  }
}

// ---------------- fc2 GEMM: 512 threads / 8 waves, 64x64 tile, wave-tile 16x32 ----------
__global__ __launch_bounds__(512) void gemm8_k(
    const u16* __restrict__ A, const u16* __restrict__ Bt,
    const u16* __restrict__ bias, const u16* __restrict__ res,
    float* __restrict__ out0, int Nn, int K)
{
  __shared__ __align__(16) u16 As[64][40];
  __shared__ __align__(16) u16 Bs[64][40];
  const int tid = threadIdx.x;
  const int m0 = blockIdx.y * 64, n0 = blockIdx.x * 64;
  const int wid = tid >> 6, lane = tid & 63;
  const int wm = (wid & 3) * 16, wn = (wid >> 2) * 32;
  const int lm = lane & 15, quad = lane >> 4;

  floatx4 zero = {0.f, 0.f, 0.f, 0.f};
  floatx4 acc0 = zero, acc1 = zero;

  const int sgrp = tid >> 8, stid = tid & 255;
  const int srow = stid >> 2, soff = (stid & 3) * 8;
  const u16* sp = sgrp ? Bt : A;
  const int sbase = sgrp ? n0 : m0;

  short8 rr;
  rr = *(const short8*)&sp[(size_t)(sbase + srow) * K + soff];
  for (int k0 = 0; k0 < K; k0 += 32) {
    if (k0) __syncthreads();
    if (sgrp) *(short8*)&Bs[srow][soff] = rr;
    else      *(short8*)&As[srow][soff] = rr;
    __syncthreads();
    if (k0 + 32 < K)
      rr = *(const short8*)&sp[(size_t)(sbase + srow) * K + k0 + 32 + soff];
    half8 fa = *(const half8*)&As[wm + lm][quad * 8];
    half8 fb0 = *(const half8*)&Bs[wn + lm][quad * 8];
    half8 fb1 = *(const half8*)&Bs[wn + 16 + lm][quad * 8];
    acc0 = MFMAG(fa, fb0, acc0);
    acc1 = MFMAG(fa, fb1, acc1);
  }

  const int rowb = m0 + wm + quad * 4;
  const int col0 = n0 + wn + lm, col1 = col0 + 16;
  const float bv0 = h2f(bias[col0]), bv1 = h2f(bias[col1]);
#pragma unroll
  for (int r = 0; r < 4; ++r) {
    const int row = rowb + r;
    const size_t o0 = (size_t)row * Nn + col0;
    const size_t o1 = (size_t)row * Nn + col1;
    out0[o0] = acc0[r] + bv0 + h2f(res[o0]);
    out0[o1] = acc1[r] + bv1 + h2f(res[o1]);
  }
}

// ---------------- fused proj + combine + bias + residual(raw x) + LayerNorm (8 waves) ----
__global__ __launch_bounds__(512) void projln8_k(
    const u16* __restrict__ A,      // attn chunks 0,1
    const u16* __restrict__ A2,     // attn chunks 2,3
    const u16* __restrict__ Bt,     // wt_proj [256 n][256 k] fp16
    const u16* __restrict__ bias,   // b_proj fp16
    const void* __restrict__ xraw,  // raw x (fp32 or bf16)
    const void* __restrict__ probew,// qkv_w for dtype probe
    const u16* __restrict__ g, const u16* __restrict__ bb,
    const float* __restrict__ muc,
    u16* __restrict__ net)
{
  __shared__ __align__(16) u16 As[16][40];
  __shared__ __align__(16) u16 Bs[256][40];
  __shared__ float ss[8][16], ssq[8][16];
  const int tid = threadIdx.x;
  const int m0 = blockIdx.x * 16;
  const int wid = tid >> 6, lane = tid & 63;
  const int lm = lane & 15, quad = lane >> 4;
  const float probe = bf2f(((const u16*)probew)[lane]);
  const bool f32 = __ballot(!(fabsf(probe) < 1000.0f)) != 0ull;

  floatx4 zero = {0.f, 0.f, 0.f, 0.f};
  floatx4 acc0 = zero, acc1 = zero;

  auto comb8 = [&](int t, int col8) -> short8 {
    const size_t o = (size_t)t * 256 + col8;
    const int h = col8 >> 5;
    const float m0_ = muc[t * 8 + h],          m1_ = muc[32768 + t * 8 + h];
    const float m2_ = muc[65536 + t * 8 + h],  m3_ = muc[98304 + t * 8 + h];
    const float M = fmaxf(fmaxf(m0_, m1_), fmaxf(m2_, m3_));
    float w0 = EX2(m0_ - M), w1 = EX2(m1_ - M), w2 = EX2(m2_ - M), w3 = EX2(m3_ - M);
    const float inv = 1.f / (w0 + w1 + w2 + w3);
    w0 *= inv; w1 *= inv; w2 *= inv; w3 *= inv;
    short8 a0 = *(const short8*)&A[o],  a1 = *(const short8*)&A[o + 1048576];
    short8 a2 = *(const short8*)&A2[o], a3 = *(const short8*)&A2[o + 1048576];
    float v[8];
#pragma unroll
    for (int j = 0; j < 8; ++j)
      v[j] = w0 * h2f((u16)a0[j]) + w1 * h2f((u16)a1[j])
           + w2 * h2f((u16)a2[j]) + w3 * h2f((u16)a3[j]);
    uint2v uu0 = {pkh2(v[0], v[1]), pkh2(v[2], v[3])};
    uint2v uu1 = {pkh2(v[4], v[5]), pkh2(v[6], v[7])};
    short8 r;
    *(uint2v*)&r = uu0; *((uint2v*)&r + 1) = uu1;
    return r;
  };

  const int arow = lane >> 2, aoff = (lane & 3) * 8;
  int brow0 = wid * 32 + (lane >> 2), brow1 = brow0 + 16;
  const int boff = (lane & 3) * 8;

  short8 ra, rb0, rb1;
  if (wid == 0) ra = comb8(m0 + arow, aoff);
  rb0 = *(const short8*)&Bt[(size_t)brow0 * 256 + boff];
  rb1 = *(const short8*)&Bt[(size_t)brow1 * 256 + boff];

  for (int k0 = 0; k0 < 256; k0 += 32) {
    if (k0) __syncthreads();
    if (wid == 0) *(short8*)&As[arow][aoff] = ra;
    *(short8*)&Bs[brow0][boff] = rb0;
    *(short8*)&Bs[brow1][boff] = rb1;
    __syncthreads();
    if (k0 + 32 < 256) {
      if (wid == 0) ra = comb8(m0 + arow, k0 + 32 + aoff);
      rb0 = *(const short8*)&Bt[(size_t)brow0 * 256 + k0 + 32 + boff];
      rb1 = *(const short8*)&Bt[(size_t)brow1 * 256 + k0 + 32 + boff];
    }
    half8 fa = *(const half8*)&As[lm][quad * 8];
    half8 fb0 = *(const half8*)&Bs[wid * 32 + lm][quad * 8];
    half8 fb1 = *(const half8*)&Bs[wid * 32 + 16 + lm][quad * 8];
    acc0 = MFMAG(fa, fb0, acc0);
    acc1 = MFMAG(fa, fb1, acc1);
  }

  const int col0 = wid * 32 + lm, col1 = col0 + 16;
  const float bv0 = h2f(bias[col0]), bv1 = h2f(bias[col1]);
  float s[4], sq[4], v0[4], v1[4];
#pragma unroll
  for (int r = 0; r < 4; ++r) {
    const int row = quad * 4 + r;
    const size_t o0 = (size_t)(m0 + row) * 256 + col0;
    const size_t o1 = (size_t)(m0 + row) * 256 + col1;
    const float x0 = f32 ? ((const float*)xraw)[o0] : bf2f(((const u16*)xraw)[o0]);
    const float x1 = f32 ? ((const float*)xraw)[o1] : bf2f(((const u16*)xraw)[o1]);
    const float a = acc0[r] + bv0 + h2f(f2h(x0));   // keep x->fp16->fp32 value path
    const float b = acc1[r] + bv1 + h2f(f2h(x1));
    v0[r] = a; v1[r] = b;
    s[r] = a + b; sq[r] = a * a + b * b;
  }
#pragma unroll
  for (int d = 1; d < 16; d <<= 1)
#pragma unroll
    for (int r = 0; r < 4; ++r) {
      s[r] += __shfl_xor(s[r], d);
      sq[r] += __shfl_xor(sq[r], d);
    }
  if (lm == 0)
#pragma unroll
    for (int r = 0; r < 4; ++r) { ss[wid][quad * 4 + r] = s[r]; ssq[wid][quad * 4 + r] = sq[r]; }
  __syncthreads();
#pragma unroll
  for (int r = 0; r < 4; ++r) {
    const int row = quad * 4 + r;
    float ts = 0.f, tq = 0.f;
#pragma unroll
    for (int w = 0; w < 8; ++w) { ts += ss[w][row]; tq += ssq[w][row]; }
    const float mean = ts * (1.f / 256.f);
    const float var = tq * (1.f / 256.f) - mean * mean;
    const float is = rsqrtf(var + 1e-5f);
    net[(size_t)(m0 + row) * 256 + col0] =
        f2h((v0[r] - mean) * is * h2f(g[col0]) + h2f(bb[col0]));
    net[(size_t)(m0 + row) * 256 + col1] =
        f2h((v1[r] - mean) * is * h2f(g[col1]) + h2f(bb[col1]));
  }
}

// ---------------- flash attention: split-K x CHUNKS, S^T form, all fp16 ----
template<int CHUNKS>
__global__ __launch_bounds__(256) void attn_k(
    const u16* __restrict__ qf16, const u16* __restrict__ kf16,
    const u16* __restrict__ vt, u16* __restrict__ outp, u16* __restrict__ out23,
    float* __restrict__ mu)
{
  __shared__ __align__(16) u16 Ks[2][64][32];
  __shared__ __align__(16) u16 Vs[2][32][64];
  const int tid = threadIdx.x, wid = tid >> 6, lane = tid & 63;
  const int lm = lane & 15, quad = lane >> 4;
  const int bid = blockIdx.x;
  const int chunk = (CHUNKS > 1) ? (bid >> 9) : 0;
  const int qblk = bid & 31, bh = (bid >> 5) & 15;
  const int b = bh >> 3, h = bh & 7;
  const int q0 = qblk * 64 + wid * 16;
  const size_t tb = (size_t)b * 2048;
  const int NT = 32 / CHUNKS;
  const int kofs = chunk * (2048 / CHUNKS);

  half8 qh;
  { size_t off = (tb + q0 + lm) * 256 + h * 32 + quad * 8;
    qh = *(const half8*)&qf16[off]; }

  const int kkey = tid >> 2, kg = tid & 3;
  const size_t kb = (tb + kofs + kkey) * 256 + h * 32 + kg * 8;
  const int vd = tid >> 3, vp = tid & 7, vk8 = vp ^ (vd & 7);
  const size_t vb = (size_t)(bh * 32 + vd) * 2048 + kofs + vk8 * 8;

  gll16(kf16 + kb, (u16*)Ks + tid * 8);
  gll16(vt  + vb,  (u16*)Vs + tid * 8);

  float mrun = -1e30f, lrun = 0.f;
  floatx4 o0 = {0.f,0.f,0.f,0.f}, o1 = {0.f,0.f,0.f,0.f};

  for (int kt = 0; kt < NT; ++kt) {
    const int buf = kt & 1;
    __syncthreads();
    if (kt < NT - 1) {
      const int nb = (buf ^ 1) * 2048;
      const size_t ko = (size_t)(kt + 1) * 16384;
      const size_t vo = (size_t)(kt + 1) * 64;
      gll16(kf16 + kb + ko, (u16*)Ks + nb + tid * 8);
      gll16(vt  + vb + vo,  (u16*)Vs + nb + tid * 8);
    }

    floatx4 z[4];
#pragma unroll
    for (int kf = 0; kf < 4; ++kf) {
      half8 khf = *(const half8*)&Ks[buf][kf * 16 + lm][quad * 8];
      floatx4 zz = {0.f,0.f,0.f,0.f};
      z[kf] = MFMAG(khf, qh, zz);
    }
    float zm = fmaxf(fmaxf(fmaxf(z[0][0], z[0][1]), fmaxf(z[0][2], z[0][3])),
               fmaxf(fmaxf(z[1][0], z[1][1]), fmaxf(z[1][2], z[1][3])));
    zm = fmaxf(zm, fmaxf(fmaxf(fmaxf(z[2][0], z[2][1]), fmaxf(z[2][2], z[2][3])),
                   fmaxf(fmaxf(z[3][0], z[3][1]), fmaxf(z[3][2], z[3][3]))));
    zm = fmaxf(zm, __shfl_xor(zm, 16));
    zm = fmaxf(zm, __shfl_xor(zm, 32));
    const float mn = fmaxf(mrun, zm);
    const float alpha = EX2((mrun - mn) * CLF);
    const float mc = mn * CLF;
    mrun = mn;
    float ls = 0.f;
    half4 pb[4];
#pragma unroll
    for (int kf = 0; kf < 4; ++kf) {
      const float p0 = EX2(__builtin_fmaf(z[kf][0], CLF, -mc));
      const float p1 = EX2(__builtin_fmaf(z[kf][1], CLF, -mc));
      const float p2 = EX2(__builtin_fmaf(z[kf][2], CLF, -mc));
      const float p3 = EX2(__builtin_fmaf(z[kf][3], CLF, -mc));
      ls += (p0 + p1) + (p2 + p3);
      uint2v uu = {pkh2(p0, p1), pkh2(p2, p3)};
      pb[kf] = *(half4*)&uu;
    }
    ls += __shfl_xor(ls, 16);
    ls += __shfl_xor(ls, 32);
    lrun = lrun * alpha + ls;
#pragma unroll
    for (int r = 0; r < 4; ++r) { o0[r] *= alpha; o1[r] *= alpha; }
    const u16* vbase = (const u16*)Vs + buf * 2048;
#pragma unroll
    for (int kf = 0; kf < 4; ++kf) {
      const int k8 = 2 * kf + (quad >> 1);
      const int d0 = lm, d1 = 16 + lm;
      half4 vf0 = *(const half4*)(vbase + (d0 * 8 + (k8 ^ (d0 & 7))) * 8 + (quad & 1) * 4);
      half4 vf1 = *(const half4*)(vbase + (d1 * 8 + (k8 ^ (d1 & 7))) * 8 + (quad & 1) * 4);
      o0 = MFMAPV(vf0, pb[kf], o0);
      o1 = MFMAPV(vf1, pb[kf], o1);
    }
  }
  const float inv = 1.0f / lrun;
  const size_t tok = tb + q0 + lm;
  u16* dst = ((CHUNKS > 2 && chunk >= 2) ? out23 : outp) + (size_t)(chunk & 1) * 1048576;
  const size_t rowo = tok * 256 + h * 32;
#pragma unroll
  for (int r = 0; r < 4; ++r) {
    dst[rowo + quad * 4 + r]      = f2h(o0[r] * inv);
    dst[rowo + 16 + quad * 4 + r] = f2h(o1[r] * inv);
  }
  if (CHUNKS > 1 && quad == 0)
    mu[chunk * 32768 + tok * 8 + h] = __builtin_fmaf(mrun, CLF, __log2f(lrun));
}

// ---------------- combine (fallback, sk2 path only) ----------------
template<int CHUNKS>
__global__ __launch_bounds__(256) void combine_k(u16* __restrict__ d,
                                                 const u16* __restrict__ e,
                                                 const float* __restrict__ mu)
{
  const int t = blockIdx.x, c = threadIdx.x, h = c >> 5;
  const size_t o = (size_t)t * 256 + c;
  float m[CHUNKS];
  float M = -1e30f;
#pragma unroll
  for (int i = 0; i < CHUNKS; ++i) { m[i] = mu[i * 32768 + t * 8 + h]; M = fmaxf(M, m[i]); }
  float wsum = 0.f, acc = 0.f;
#pragma unroll
  for (int i = 0; i < CHUNKS; ++i) {
    const float w = EX2(m[i] - M);
    const u16 v = (i < 2) ? d[o + (size_t)i * 1048576] : e[o + (size_t)(i - 2) * 1048576];
    wsum += w; acc += w * h2f(v);
  }
  d[o] = f2h(acc / wsum);
}

// ---------------- residual add + LayerNorm (fallback paths only) ----------------
__global__ __launch_bounds__(256) void ln_k(const float* __restrict__ pf,
                                            const u16* __restrict__ xh,
                                            const u16* __restrict__ g,
                                            const u16* __restrict__ bta,
                                            u16* __restrict__ net)
{
  const int t = blockIdx.x, c = threadIdx.x;
  const size_t o = (size_t)t * 256 + c;
  float v = pf[o] + h2f(xh[o]);
  float s = v, s2 = v * v;
#pragma unroll
  for (int d = 1; d < 64; d <<= 1) { s += __shfl_xor(s, d); s2 += __shfl_xor(s2, d); }
  __shared__ float ss[4], ss2[4];
  const int w = c >> 6;
  if ((c & 63) == 0) { ss[w] = s; ss2[w] = s2; }
  __syncthreads();
  s = ss[0] + ss[1] + ss[2] + ss[3];
  s2 = ss2[0] + ss2[1] + ss2[2] + ss2[3];
  const float mu = s * (1.f / 256.f);
  const float var = s2 * (1.f / 256.f) - mu * mu;
  const float is = rsqrtf(var + 1e-5f);
  net[o] = f2h((v - mu) * is * h2f(g[c]) + h2f(bta[c]));
}

extern "C" void kernel_launch(void* const* d_in, const int* in_sizes, int n_in,
                              void* d_out, int out_size, void* d_ws, size_t ws_size,
                              hipStream_t stream) {
  const void* x      = d_in[0];
  const void* qkv_w  = d_in[1];
  const void* proj_w = d_in[2];
  const void* proj_b = d_in[3];
  const void* fc1_w  = d_in[4];
  const void* fc1_b  = d_in[5];
  const void* fc2_w  = d_in[6];
  const void* fc2_b  = d_in[7];
  const void* ln_g   = d_in[8];
  const void* ln_b   = d_in[9];

  char* ws = (char*)d_ws;
  u16* b_proj  = (u16*)(ws + 4096);
  u16* b_fc1   = (u16*)(ws + 8192);
  u16* b_fc2   = (u16*)(ws + 12288);
  u16* g_ln    = (u16*)(ws + 16384);
  u16* bb_ln   = (u16*)(ws + 20480);
  u16* wq_f    = (u16*)(ws + 131072);    // fallback only
  u16* wt_proj = (u16*)(ws + 524288);
  u16* wt_fc1  = (u16*)(ws + 655360);
  u16* wt_fc2  = (u16*)(ws + 1179648);
  u16* x_f     = (u16*)(ws + 2097152);   // fallback only
  u16* q_f16   = (u16*)(ws + 4194304);
  u16* k_f16   = (u16*)(ws + 6291456);
  u16* vt      = (u16*)(ws + 8388608);
  float* mu    = (float*)(ws + 10485760);
  u16* out23   = (u16*)(ws + 11010048);
  u16* attn    = (u16*)d_out;            // chunks 0,1 (d_out scratch until fc2)

  // sk4 path: net over the (now unused) x_f region; hbuf over dead q/k/vt/mu
  u16* net4    = (u16*)(ws + 2097152);
  u16* hbuf4   = (u16*)(ws + 4194304);

  // fallback-path buffers
  float* projf = (float*)(ws + 4194304);
  u16* net     = (u16*)(ws + 11010048);
  u16* hbuf    = (u16*)(ws + 2097152);

  const bool sk4 = ws_size >= 15204352;    // call-invariant -> graph-safe
  const bool sk2 = ws_size >= 11010048;

  if (sk4) {
    qkvprep_k<<<920, 256, 0, stream>>>(x, qkv_w, proj_w, fc1_w, fc2_w,
                                       proj_b, fc1_b, fc2_b, ln_g, ln_b,
                                       wt_proj, wt_fc1, wt_fc2,
                                       b_proj, b_fc1, b_fc2, g_ln, bb_ln,
                                       vt, q_f16, k_f16);
    attn_k<4><<<2048, 256, 0, stream>>>(q_f16, k_f16, vt, attn, out23, mu);
    projln8_k<<<256, 512, 0, stream>>>(attn, out23, wt_proj, b_proj, x, qkv_w,
                                       g_ln, bb_ln, mu, net4);
    gemm_k<2, 1, true, false, false><<<dim3(16, 64), 256, 0, stream>>>(
        net4, wt_fc1, nullptr, b_fc1, nullptr, hbuf4, nullptr, nullptr, nullptr,
        4096, 1024, 256);
    gemm8_k<<<dim3(4, 64), 512, 0, stream>>>(
        hbuf4, wt_fc2, b_fc2, net4, (float*)d_out, 256, 1024);
    return;
  }

  prep_k<<<1224, 256, 0, stream>>>(x, qkv_w, proj_w, fc1_w, fc2_w,
                                   proj_b, fc1_b, fc2_b, ln_g, ln_b,
                                   x_f, wq_f, wt_proj, wt_fc1, wt_fc2,
                                   b_proj, b_fc1, b_fc2, g_ln, bb_ln);
  gemm_k<2, 2, false, false, false><<<dim3(12, 64), 256, 0, stream>>>(
      x_f, wq_f, nullptr, nullptr, nullptr, vt, q_f16, k_f16, nullptr, 4096, 768, 256);
  if (sk2) {
    attn_k<2><<<1024, 256, 0, stream>>>(q_f16, k_f16, vt, attn, nullptr, mu);
    combine_k<2><<<4096, 256, 0, stream>>>(attn, nullptr, mu);
    gemm_k<2, 0, true, false, false><<<dim3(4, 64), 256, 0, stream>>>(
        attn, wt_proj, nullptr, b_proj, nullptr, projf, nullptr, nullptr, nullptr,
        4096, 256, 256);
  } else {
    attn_k<1><<<512, 256, 0, stream>>>(q_f16, k_f16, vt, attn, nullptr, nullptr);
    gemm_k<2, 0, true, false, false><<<dim3(4, 64), 256, 0, stream>>>(
        attn, wt_proj, nullptr, b_proj, nullptr, projf, nullptr, nullptr, nullptr,
        4096, 256, 256);
  }
  ln_k<<<4096, 256, 0, stream>>>(projf, x_f, g_ln, bb_ln, net);
  gemm_k<2, 1, true, false, false><<<dim3(16, 64), 256, 0, stream>>>(
      net, wt_fc1, nullptr, b_fc1, nullptr, hbuf, nullptr, nullptr, nullptr,
      4096, 1024, 256);
  gemm_k<2, 0, true, true, false><<<dim3(4, 64), 256, 0, stream>>>(
      hbuf, wt_fc2, nullptr, b_fc2, net, d_out, nullptr, nullptr, nullptr,
      4096, 256, 1024);
}